// Round 5
// baseline (446.889 us; speedup 1.0000x reference)
//
#include <hip/hip_runtime.h>

#define NN 100000
#define NE 1600000
#define DIM0 11
#define H 128
#define NL 4
#define NG 4096
#define EPS 1e-5f

#define NBKT 391       // buckets of 256 nodes: bucket = dst >> 8
#define CAP 5120       // fixed bucket capacity (mean 4096, sigma 64 -> 16 sigma)
#define EPB 4096       // edges per block in scatter phase
static constexpr int NBB = (NE + EPB - 1) / EPB;  // 391

typedef _Float16 f16x8 __attribute__((ext_vector_type(8)));
typedef _Float16 f16x2 __attribute__((ext_vector_type(2)));
typedef float f32x4 __attribute__((ext_vector_type(4)));
typedef float f32x2 __attribute__((ext_vector_type(2)));

// r17 post-mortem: 8-deep per-stream MLP inflated FETCH 102.8->119MB (L2 hit
// drop from wider live window) at flat dur -> within-wave depth is the wrong
// knob. r18 (this round): cross-wave TLP instead. Quarter-PAIR owns a node
// (odd/even edge split + one shfl_xor(16) combine); wave = 8 nodes; block =
// 128thr/16 nodes; 12500 waves total (was 6250, grid was the occupancy
// limit at 50%). Depth back to r16-proven 4. Phase 2 (MFMA/LN/epilogue)
// unchanged, run by wave 0 per block after one __syncthreads.
// Build: deg fused into k_bscatter (global atomics) -> k_bcsr single-pass.

// ---- fp8 helpers (OCP e4m3 on gfx950) ----

__device__ __forceinline__ uint2 pack_fp8x8(const float* v) {
    int lo = 0, hi = 0;
    lo = __builtin_amdgcn_cvt_pk_fp8_f32(v[0], v[1], lo, false);
    lo = __builtin_amdgcn_cvt_pk_fp8_f32(v[2], v[3], lo, true);
    hi = __builtin_amdgcn_cvt_pk_fp8_f32(v[4], v[5], hi, false);
    hi = __builtin_amdgcn_cvt_pk_fp8_f32(v[6], v[7], hi, true);
    return (uint2){(unsigned)lo, (unsigned)hi};
}

__device__ __forceinline__ void acc_fp8x8(uint2 u, f32x2* a2) {
    a2[0] += __builtin_amdgcn_cvt_pk_f32_fp8((int)u.x, false);
    a2[1] += __builtin_amdgcn_cvt_pk_f32_fp8((int)u.x, true);
    a2[2] += __builtin_amdgcn_cvt_pk_f32_fp8((int)u.y, false);
    a2[3] += __builtin_amdgcn_cvt_pk_f32_fp8((int)u.y, true);
}

// ---------------- init ----------------

__global__ void k_init(int* __restrict__ bfill, int* __restrict__ gstart, int* __restrict__ gend,
                       int* __restrict__ deg) {
    int i = blockIdx.x * 256 + threadIdx.x;
    if (i <= NBKT) bfill[i] = 0;
    if (i < NG) { gstart[i] = 0x7fffffff; gend[i] = 0; }
    if (i < NN) deg[i] = 0;
}

// ---------------- bucketed CSR build ----------------

__global__ __launch_bounds__(256) void k_bscatter(const int* __restrict__ src, const int* __restrict__ dst,
                                                  int* __restrict__ bfill, unsigned int* __restrict__ ebuf,
                                                  int* __restrict__ deg) {
    __shared__ int lc[NBKT];
    __shared__ int lbase[NBKT];
    int t = threadIdx.x;
    for (int i = t; i < NBKT; i += 256) lc[i] = 0;
    __syncthreads();
    int base = blockIdx.x * EPB;
    int rank[16];
    int bk[16];
    unsigned pk[16];
#pragma unroll
    for (int i = 0; i < 16; i++) {
        int e = base + i * 256 + t;
        if (e < NE) {
            int d = dst[e];
            int s = src[e];
            int b = d >> 8;
            bk[i] = b;
            pk[i] = (unsigned)s | ((unsigned)(d & 255) << 17);
            rank[i] = atomicAdd(&lc[b], 1);
            atomicAdd(&deg[d], 1);
        } else bk[i] = -1;
    }
    __syncthreads();
    for (int i = t; i < NBKT; i += 256)
        lbase[i] = i * CAP + (lc[i] ? atomicAdd(&bfill[i], lc[i]) : 0);
    __syncthreads();
#pragma unroll
    for (int i = 0; i < 16; i++) {
        if (bk[i] >= 0)
            ebuf[lbase[bk[i]] + rank[i]] = pk[i];
    }
}

// One block per bucket (391 blocks): deg -> dis + scan -> rps/rpe, one ebuf
// pass -> col. (Count pass eliminated: deg computed in k_bscatter.)
__global__ __launch_bounds__(256) void k_bcsr(const unsigned int* __restrict__ ebuf,
                                              const int* __restrict__ bfill,
                                              const int* __restrict__ deg,
                                              int* __restrict__ rps, int* __restrict__ rpe,
                                              int* __restrict__ col, float* __restrict__ dis) {
    __shared__ int lcnt[256];
    __shared__ int lfill[256];
    __shared__ int tmp[256];
    int t = threadIdx.x;
    int b = blockIdx.x;
    int cb = b * CAP;
    int ecnt = bfill[b];
    int n0 = b << 8;
    int nb = min(256, NN - n0);

    int v = (t < nb) ? deg[n0 + t] : 0;
    lfill[t] = 0;
    if (t < nb) dis[n0 + t] = rsqrtf((float)(v + 1));

    tmp[t] = v;
    __syncthreads();
    for (int off = 1; off < 256; off <<= 1) {
        int x = (t >= off) ? tmp[t - off] : 0;
        __syncthreads();
        tmp[t] += x;
        __syncthreads();
    }
    lcnt[t] = tmp[t] - v;   // exclusive scan
    __syncthreads();

    if (t < nb) {
        rps[n0 + t] = cb + lcnt[t];
        rpe[n0 + t] = cb + ((t < 255) ? lcnt[t + 1] : ecnt);
    }

    for (int i = t; i < ecnt; i += 256) {
        unsigned p = ebuf[cb + i];
        int dl = p >> 17;
        int s = (int)(p & 0x1FFFFu);
        col[cb + lcnt[dl] + atomicAdd(&lfill[dl], 1)] = s;
    }
}

// ---------------- embed: hh = fp16(relu(x @ W_embed + b)); hp = fp8(hh * dis) ----------------

__global__ __launch_bounds__(256) void k_embed(const float* __restrict__ x, const float* __restrict__ W,
                                               const float* __restrict__ b, _Float16* __restrict__ hh,
                                               const float* __restrict__ dis, uint2* __restrict__ hp) {
    __shared__ float Ws[DIM0 * H];
    __shared__ float bs[H];
    __shared__ float xs[16 * DIM0];
    int tid = threadIdx.x;
    for (int i = tid; i < DIM0 * H; i += 256) Ws[i] = W[i];
    if (tid < H) bs[tid] = b[tid];
    if (tid < 16 * DIM0) xs[tid] = x[(size_t)blockIdx.x * (16 * DIM0) + tid];
    __syncthreads();
    int nl = tid >> 4;
    int node = blockIdx.x * 16 + nl;
    int l4 = tid & 15;
    float dn = dis[node];
    f16x8 o;
    float hv[8];
#pragma unroll
    for (int j = 0; j < 8; j++) {
        int c = l4 * 8 + j;
        float acc = bs[c];
#pragma unroll
        for (int k = 0; k < DIM0; k++) acc += xs[nl * DIM0 + k] * Ws[k * H + c];
        float r = fmaxf(acc, 0.f);
        o[j] = (_Float16)r;
        hv[j] = r * dn;
    }
    *(f16x8*)&hh[(size_t)node * H + l4 * 8] = o;
    hp[(size_t)node * 16 + l4] = pack_fp8x8(hv);
}

// ---------------- W pack: W[l][k][n] fp32 -> B-fragment-layout fp16 ----------------

__global__ __launch_bounds__(256) void k_wpack(const float* __restrict__ W, _Float16* __restrict__ Wp) {
    int t = blockIdx.x * 256 + threadIdx.x;   // 8192 threads
    int lane = t & 63;
    int idx = t >> 6;          // 0..127
    int nt = idx & 7;
    int ks = (idx >> 3) & 3;
    int l = idx >> 5;
    int q = lane >> 4, l15 = lane & 15;
    const float* Wl = W + (size_t)l * H * H;
    _Float16* o = Wp + (size_t)idx * 512 + lane * 8;
#pragma unroll
    for (int j = 0; j < 8; j++)
        o[j] = (_Float16)(Wl[(ks * 32 + q * 8 + j) * H + nt * 16 + l15]);
}

// ---------------- fused layer: hout = relu(LN(agg(hin) @ W + b)) + hin ----------------
// Phase 1: quarter-PAIR per node (odd/even edge split, shfl_xor(16) combine),
// 8 nodes/wave, 16 nodes/block (2 waves), 12500 waves chip-wide. Depth-4.
// Phase 2: wave 0 only, unchanged 16-node MFMA + LN + epilogue.

__global__ __launch_bounds__(128, 8) void k_layer(const _Float16* __restrict__ hin,
                                                  _Float16* __restrict__ hout,
                                                  const uint2* __restrict__ hpin,
                                                  uint2* __restrict__ hpout,
                                                  const float* __restrict__ dis, const int* __restrict__ rps,
                                                  const int* __restrict__ rpe, const int* __restrict__ col,
                                                  const _Float16* __restrict__ Wp,
                                                  const float* __restrict__ bias,
                                                  const float* __restrict__ gamma,
                                                  const float* __restrict__ beta,
                                                  int store_hp) {
    __shared__ _Float16 Ls[16][136];   // 4352 B
    int tid = threadIdx.x;
    int wave = tid >> 6;
    int lane = tid & 63;
    int q = lane >> 4, l4 = lane & 15;
    int half = q & 1;
    int nbb = blockIdx.x * 16;          // block's 16 nodes (16 | NN, no tail)
    int nbase = nbb + wave * 8;         // this wave's 8 nodes

    // wave-wide prefetch of the 8 nodes' CSR ranges + dis
    int l8 = lane & 7;
    int ev0 = rps[nbase + l8];
    int ev1 = rpe[nbase + l8];
    float dv = dis[nbase + l8];

    // ---- phase 1: gather 8 nodes, 2 per round; quarter-pair splits edges ----
#pragma unroll 1
    for (int r = 0; r < 4; r++) {
        int nl = r * 2 + (q >> 1);      // node slot 0..7 within wave
        int e0 = __shfl(ev0, nl, 64);
        int e1 = __shfl(ev1, nl, 64);
        float dn = __shfl(dv, nl, 64);
        int node = nbase + nl;

        f32x2 a2[4];
#pragma unroll
        for (int j = 0; j < 4; j++) a2[j] = (f32x2){0.f, 0.f};

        uint2 sv;
        if (half) sv = hpin[(size_t)node * 16 + l4];   // self row on odd half

        int e = e0 + half;              // odd/even interleave
#pragma unroll 1
        for (; e + 6 < e1; e += 8) {    // 4 edges per half per iter
            int s0 = col[e];
            int s1 = col[e + 2];
            int s2 = col[e + 4];
            int s3 = col[e + 6];
            uint2 v0 = hpin[(size_t)s0 * 16 + l4];
            uint2 v1 = hpin[(size_t)s1 * 16 + l4];
            uint2 v2 = hpin[(size_t)s2 * 16 + l4];
            uint2 v3 = hpin[(size_t)s3 * 16 + l4];
            acc_fp8x8(v0, a2);
            acc_fp8x8(v1, a2);
            acc_fp8x8(v2, a2);
            acc_fp8x8(v3, a2);
        }
#pragma unroll 1
        for (; e < e1; e += 2) {
            int s = col[e];
            uint2 v = hpin[(size_t)s * 16 + l4];
            acc_fp8x8(v, a2);
        }
        if (half) acc_fp8x8(sv, a2);    // self-loop once per node

        // combine the two halves (q0<->q1, q2<->q3)
#pragma unroll
        for (int j = 0; j < 4; j++) {
            float x0 = a2[j][0], x1 = a2[j][1];
            x0 += __shfl_xor(x0, 16, 64);
            x1 += __shfl_xor(x1, 16, 64);
            a2[j][0] = x0; a2[j][1] = x1;
        }
        if (!half) {
            f16x8 o;
#pragma unroll
            for (int j = 0; j < 4; j++) {
                o[2 * j]     = (_Float16)(a2[j][0] * dn);
                o[2 * j + 1] = (_Float16)(a2[j][1] * dn);
            }
            *(f16x8*)&Ls[wave * 8 + nl][l4 * 8] = o;
        }
    }

    __syncthreads();
    if (wave == 1) return;   // no further barriers; wave 0 finishes the block

    // ---- phase 2: read A-fragments into registers, then GEMM + LN (Ls reused) ----
    f16x8 af[4];
#pragma unroll
    for (int ks = 0; ks < 4; ks++)
        af[ks] = *(const f16x8*)&Ls[l4][ks * 32 + q * 8];

    float bb[8], gm[8], bt[8];
#pragma unroll
    for (int nt = 0; nt < 8; nt++) {
        bb[nt] = bias[nt * 16 + l4];
        gm[nt] = gamma[nt * 16 + l4];
        bt[nt] = beta[nt * 16 + l4];
    }

    const f16x8* wp8 = (const f16x8*)Wp;
    f32x4 acc[8];
#pragma unroll
    for (int nt = 0; nt < 8; nt++) {
        acc[nt] = (f32x4){0.f, 0.f, 0.f, 0.f};
#pragma unroll
        for (int ks = 0; ks < 4; ks++) {
            f16x8 bf = wp8[(ks * 8 + nt) * 64 + lane];
            acc[nt] = __builtin_amdgcn_mfma_f32_16x16x32_f16(af[ks], bf, acc[nt], 0, 0, 0);
        }
#pragma unroll
        for (int r = 0; r < 4; r++) acc[nt][r] += bb[nt];
    }

    float mu[4], rs[4];
#pragma unroll
    for (int r = 0; r < 4; r++) {
        float s = 0.f;
#pragma unroll
        for (int nt = 0; nt < 8; nt++) s += acc[nt][r];
#pragma unroll
        for (int off = 8; off > 0; off >>= 1) s += __shfl_xor(s, off, 64);
        mu[r] = s * (1.f / 128.f);
    }
#pragma unroll
    for (int r = 0; r < 4; r++) {
        float v = 0.f;
#pragma unroll
        for (int nt = 0; nt < 8; nt++) {
            float d = acc[nt][r] - mu[r];
            v += d * d;
        }
#pragma unroll
        for (int off = 8; off > 0; off >>= 1) v += __shfl_xor(v, off, 64);
        rs[r] = rsqrtf(v * (1.f / 128.f) + EPS);
    }

    // overwrite Ls with LN output (af already in registers)
#pragma unroll
    for (int nt = 0; nt < 8; nt++)
#pragma unroll
        for (int r = 0; r < 4; r++) {
            float o = fmaxf((acc[nt][r] - mu[r]) * rs[r] * gm[nt] + bt[nt], 0.f);
            Ls[q * 4 + r][nt * 16 + l4] = (_Float16)o;
        }

    // epilogue: residual add (hin) + coalesced store to hout + fp8 gather copy
    float dve = dis[nbb + (lane & 15)];
    const f16x8* hi8 = (const f16x8*)hin;
    f16x8* ho8 = (f16x8*)hout;
#pragma unroll
    for (int it = 0; it < 4; it++) {
        int c = it * 64 + lane;
        int rr = c >> 4, ck = c & 15;   // rr = it*4 + q
        int row = nbb + rr;
        f16x8 ln = *(const f16x8*)&Ls[rr][ck * 8];
        f16x8 res = hi8[(size_t)row * 16 + ck];
        float dn2 = __shfl(dve, rr, 64);
        f16x8 o;
        float hv[8];
#pragma unroll
        for (int j = 0; j < 8; j++) {
            float s = (float)ln[j] + (float)res[j];
            o[j] = (_Float16)s;
            hv[j] = s * dn2;
        }
        ho8[(size_t)row * 16 + ck] = o;
        if (store_hp)
            hpout[(size_t)row * 16 + ck] = pack_fp8x8(hv);
    }
}

// ---------------- pooling ----------------

__global__ void k_range(const int* __restrict__ batch, int* __restrict__ gstart, int* __restrict__ gend) {
    int n = blockIdx.x * 256 + threadIdx.x;
    if (n < NN) {
        int g = batch[n];
        atomicMin(&gstart[g], n);
        atomicMax(&gend[g], n + 1);
    }
}

// One wave per graph; lane = (node slot p4, col group l4); f16x8 loads, 4 nodes/iter.
__global__ __launch_bounds__(256) void k_pool(const _Float16* __restrict__ hh, const int* __restrict__ gstart,
                                              const int* __restrict__ gend, const float* __restrict__ Wout,
                                              const float* __restrict__ bout, float* __restrict__ out) {
    int tid = threadIdx.x;
    int lane = tid & 63;
    int p4 = lane >> 4;     // node slot 0..3
    int l4 = lane & 15;     // cols l4*8 .. +7
    int g = blockIdx.x * 4 + (tid >> 6);
    if (g >= NG) return;

    int s = gstart[g], e = gend[g];
    const f16x8* h8 = (const f16x8*)hh;
    float acc[8];
#pragma unroll
    for (int j = 0; j < 8; j++) acc[j] = 0.f;
    for (int n = s + p4; n < e; n += 4) {
        f16x8 v = h8[(size_t)n * 16 + l4];
#pragma unroll
        for (int j = 0; j < 8; j++) acc[j] += (float)v[j];
    }
    // combine node slots
#pragma unroll
    for (int j = 0; j < 8; j++) {
        acc[j] += __shfl_xor(acc[j], 16, 64);
        acc[j] += __shfl_xor(acc[j], 32, 64);
    }
    float p = 0.f;
#pragma unroll
    for (int j = 0; j < 8; j++) p += acc[j] * Wout[l4 * 8 + j];
    // reduce across the 16 col groups
#pragma unroll
    for (int off = 8; off > 0; off >>= 1) p += __shfl_xor(p, off, 64);
    if (lane == 0) {
        float inv = 1.f / (float)max(e - s, 1);
        out[g] = p * inv + bout[0];
    }
}

// ---------------- launcher ----------------

extern "C" void kernel_launch(void* const* d_in, const int* in_sizes, int n_in,
                              void* d_out, int out_size, void* d_ws, size_t ws_size,
                              hipStream_t stream) {
    const float* x       = (const float*)d_in[0];
    const int*   edge    = (const int*)d_in[1];
    const int*   batch   = (const int*)d_in[2];
    const float* W_embed = (const float*)d_in[3];
    const float* b_embed = (const float*)d_in[4];
    const float* W_gnn   = (const float*)d_in[5];
    const float* b_gnn   = (const float*)d_in[6];
    const float* gamma   = (const float*)d_in[7];
    const float* beta    = (const float*)d_in[8];
    const float* W_out   = (const float*)d_in[9];
    const float* b_out   = (const float*)d_in[10];
    float* out = (float*)d_out;

    char* ws = (char*)d_ws;
    size_t off = 0;
    auto alloc = [&](size_t bytes) -> char* {
        char* p = ws + off;
        off += (bytes + 255) & ~(size_t)255;
        return p;
    };
    _Float16*     hh0  = (_Float16*)alloc((size_t)NN * H * 2);
    _Float16*     hh1  = (_Float16*)alloc((size_t)NN * H * 2);
    uint2*        hp0  = (uint2*)alloc((size_t)NN * H);       // fp8 gather copies
    uint2*        hp1  = (uint2*)alloc((size_t)NN * H);
    _Float16*     Wp   = (_Float16*)alloc((size_t)NL * 4 * 8 * 512 * 2);
    float*        dis  = (float*)alloc((size_t)NN * 4);
    int*          rps  = (int*)alloc((size_t)NN * 4);
    int*          rpe  = (int*)alloc((size_t)NN * 4);
    int*          deg  = (int*)alloc((size_t)NN * 4);
    int*          col  = (int*)alloc((size_t)NBKT * CAP * 4);
    unsigned int* ebuf = (unsigned int*)alloc((size_t)NBKT * CAP * 4);
    int*          bfill = (int*)alloc((NBKT + 1) * 4);
    int*   gstart = (int*)alloc((size_t)NG * 4);
    int*   gend   = (int*)alloc((size_t)NG * 4);

    const int* srcp = edge;
    const int* dstp = edge + NE;

    k_init<<<(NN + 255) / 256, 256, 0, stream>>>(bfill, gstart, gend, deg);
    k_bscatter<<<NBB, 256, 0, stream>>>(srcp, dstp, bfill, ebuf, deg);
    k_bcsr<<<NBKT, 256, 0, stream>>>(ebuf, bfill, deg, rps, rpe, col, dis);

    k_wpack<<<32, 256, 0, stream>>>(W_gnn, Wp);
    k_embed<<<NN / 16, 256, 0, stream>>>(x, W_embed, b_embed, hh0, dis, hp0);

    // ping-pong: L0 hh0->hh1, L1 hh1->hh0, L2 hh0->hh1, L3 hh1->hh0
    _Float16* hb[2] = {hh0, hh1};
    uint2*    hp[2] = {hp0, hp1};
    for (int l = 0; l < NL; l++) {
        k_layer<<<NN / 16, 128, 0, stream>>>(hb[l & 1], hb[(l & 1) ^ 1],
                                             hp[l & 1], hp[(l & 1) ^ 1],
                                             dis, rps, rpe, col,
                                             Wp + (size_t)l * 4 * 8 * 512,
                                             b_gnn + l * H, gamma + l * H, beta + l * H,
                                             (l != NL - 1) ? 1 : 0);
    }

    k_range<<<(NN + 255) / 256, 256, 0, stream>>>(batch, gstart, gend);
    k_pool<<<NG / 4, 256, 0, stream>>>(hh0, gstart, gend, W_out, b_out, out);
}

// Round 6
// 404.384 us; speedup vs baseline: 1.1051x; 1.1051x over previous
//
#include <hip/hip_runtime.h>

#define NN 100000
#define NE 1600000
#define DIM0 11
#define H 128
#define NL 4
#define NG 4096
#define EPS 1e-5f

#define NBKT 391       // buckets of 256 nodes: bucket = dst >> 8
#define CAP 5120       // fixed bucket capacity (mean 4096, sigma 64 -> 16 sigma)
#define EPB 2048       // edges per block in scatter phase (r19: was 4096; more TLP)
static constexpr int NBB = (NE + EPB - 1) / EPB;  // 782

typedef _Float16 f16x8 __attribute__((ext_vector_type(8)));
typedef _Float16 f16x2 __attribute__((ext_vector_type(2)));
typedef float f32x4 __attribute__((ext_vector_type(4)));
typedef float f32x2 __attribute__((ext_vector_type(2)));

// r18 post-mortem: deg fused via global atomicAdd = 1.6M cross-XCD atomic
// RMWs on a 400KB array -> lines ping-pong through HBM (WRITE_SIZE 59.6MB vs
// 6.4MB of real data), k_bscatter 77us. REVERTED to r17 two-pass k_bcsr
// (per-bucket LDS-atomic counting). k_bscatter EPB 4096->2048: 13% occupancy
// was latency-bound, halve serial chain / double TLP.
// k_layer keeps the r18 shape (8 nodes/wave, 2-wave block, quarter-pair per
// node) for clean attribution this round. Decision rule: >59.5us -> revert
// to r16 shape next round.

// ---- fp8 helpers (OCP e4m3 on gfx950) ----

__device__ __forceinline__ uint2 pack_fp8x8(const float* v) {
    int lo = 0, hi = 0;
    lo = __builtin_amdgcn_cvt_pk_fp8_f32(v[0], v[1], lo, false);
    lo = __builtin_amdgcn_cvt_pk_fp8_f32(v[2], v[3], lo, true);
    hi = __builtin_amdgcn_cvt_pk_fp8_f32(v[4], v[5], hi, false);
    hi = __builtin_amdgcn_cvt_pk_fp8_f32(v[6], v[7], hi, true);
    return (uint2){(unsigned)lo, (unsigned)hi};
}

__device__ __forceinline__ void acc_fp8x8(uint2 u, f32x2* a2) {
    a2[0] += __builtin_amdgcn_cvt_pk_f32_fp8((int)u.x, false);
    a2[1] += __builtin_amdgcn_cvt_pk_f32_fp8((int)u.x, true);
    a2[2] += __builtin_amdgcn_cvt_pk_f32_fp8((int)u.y, false);
    a2[3] += __builtin_amdgcn_cvt_pk_f32_fp8((int)u.y, true);
}

// ---------------- init ----------------

__global__ void k_init(int* __restrict__ bfill, int* __restrict__ gstart, int* __restrict__ gend) {
    int i = blockIdx.x * 256 + threadIdx.x;
    if (i <= NBKT) bfill[i] = 0;
    if (i < NG) { gstart[i] = 0x7fffffff; gend[i] = 0; }
}

// ---------------- bucketed CSR build ----------------

__global__ __launch_bounds__(256) void k_bscatter(const int* __restrict__ src, const int* __restrict__ dst,
                                                  int* __restrict__ bfill, unsigned int* __restrict__ ebuf) {
    __shared__ int lc[NBKT];
    __shared__ int lbase[NBKT];
    int t = threadIdx.x;
    for (int i = t; i < NBKT; i += 256) lc[i] = 0;
    __syncthreads();
    int base = blockIdx.x * EPB;
    int rank[8];
    int bk[8];
    unsigned pk[8];
#pragma unroll
    for (int i = 0; i < 8; i++) {
        int e = base + i * 256 + t;
        if (e < NE) {
            int d = dst[e];
            int s = src[e];
            int b = d >> 8;
            bk[i] = b;
            pk[i] = (unsigned)s | ((unsigned)(d & 255) << 17);
            rank[i] = atomicAdd(&lc[b], 1);
        } else bk[i] = -1;
    }
    __syncthreads();
    for (int i = t; i < NBKT; i += 256)
        lbase[i] = i * CAP + (lc[i] ? atomicAdd(&bfill[i], lc[i]) : 0);
    __syncthreads();
#pragma unroll
    for (int i = 0; i < 8; i++) {
        if (bk[i] >= 0)
            ebuf[lbase[bk[i]] + rank[i]] = pk[i];
    }
}

// One block per bucket (391 blocks): count -> dis, scan -> rps/rpe, scatter -> col.
__global__ __launch_bounds__(256) void k_bcsr(const unsigned int* __restrict__ ebuf,
                                              const int* __restrict__ bfill,
                                              int* __restrict__ rps, int* __restrict__ rpe,
                                              int* __restrict__ col, float* __restrict__ dis) {
    __shared__ int lcnt[256];
    __shared__ int lfill[256];
    __shared__ int tmp[256];
    int t = threadIdx.x;
    int b = blockIdx.x;
    int cb = b * CAP;
    int ecnt = bfill[b];
    int n0 = b << 8;
    int nb = min(256, NN - n0);

    lcnt[t] = 0;
    lfill[t] = 0;
    __syncthreads();

    for (int i = t; i < ecnt; i += 256) {
        unsigned p = ebuf[cb + i];
        atomicAdd(&lcnt[p >> 17], 1);
    }
    __syncthreads();

    if (t < nb) dis[n0 + t] = rsqrtf((float)(lcnt[t] + 1));

    int v = lcnt[t];
    tmp[t] = v;
    __syncthreads();
    for (int off = 1; off < 256; off <<= 1) {
        int x = (t >= off) ? tmp[t - off] : 0;
        __syncthreads();
        tmp[t] += x;
        __syncthreads();
    }
    lcnt[t] = tmp[t] - v;   // exclusive scan
    __syncthreads();

    if (t < nb) {
        rps[n0 + t] = cb + lcnt[t];
        rpe[n0 + t] = cb + ((t < 255) ? lcnt[t + 1] : ecnt);
    }

    for (int i = t; i < ecnt; i += 256) {
        unsigned p = ebuf[cb + i];
        int dl = p >> 17;
        int s = (int)(p & 0x1FFFFu);
        col[cb + lcnt[dl] + atomicAdd(&lfill[dl], 1)] = s;
    }
}

// ---------------- embed: hh = fp16(relu(x @ W_embed + b)); hp = fp8(hh * dis) ----------------

__global__ __launch_bounds__(256) void k_embed(const float* __restrict__ x, const float* __restrict__ W,
                                               const float* __restrict__ b, _Float16* __restrict__ hh,
                                               const float* __restrict__ dis, uint2* __restrict__ hp) {
    __shared__ float Ws[DIM0 * H];
    __shared__ float bs[H];
    __shared__ float xs[16 * DIM0];
    int tid = threadIdx.x;
    for (int i = tid; i < DIM0 * H; i += 256) Ws[i] = W[i];
    if (tid < H) bs[tid] = b[tid];
    if (tid < 16 * DIM0) xs[tid] = x[(size_t)blockIdx.x * (16 * DIM0) + tid];
    __syncthreads();
    int nl = tid >> 4;
    int node = blockIdx.x * 16 + nl;
    int l4 = tid & 15;
    float dn = dis[node];
    f16x8 o;
    float hv[8];
#pragma unroll
    for (int j = 0; j < 8; j++) {
        int c = l4 * 8 + j;
        float acc = bs[c];
#pragma unroll
        for (int k = 0; k < DIM0; k++) acc += xs[nl * DIM0 + k] * Ws[k * H + c];
        float r = fmaxf(acc, 0.f);
        o[j] = (_Float16)r;
        hv[j] = r * dn;
    }
    *(f16x8*)&hh[(size_t)node * H + l4 * 8] = o;
    hp[(size_t)node * 16 + l4] = pack_fp8x8(hv);
}

// ---------------- W pack: W[l][k][n] fp32 -> B-fragment-layout fp16 ----------------

__global__ __launch_bounds__(256) void k_wpack(const float* __restrict__ W, _Float16* __restrict__ Wp) {
    int t = blockIdx.x * 256 + threadIdx.x;   // 8192 threads
    int lane = t & 63;
    int idx = t >> 6;          // 0..127
    int nt = idx & 7;
    int ks = (idx >> 3) & 3;
    int l = idx >> 5;
    int q = lane >> 4, l15 = lane & 15;
    const float* Wl = W + (size_t)l * H * H;
    _Float16* o = Wp + (size_t)idx * 512 + lane * 8;
#pragma unroll
    for (int j = 0; j < 8; j++)
        o[j] = (_Float16)(Wl[(ks * 32 + q * 8 + j) * H + nt * 16 + l15]);
}

// ---------------- fused layer: hout = relu(LN(agg(hin) @ W + b)) + hin ----------------
// Phase 1: quarter-PAIR per node (odd/even edge split, shfl_xor(16) combine),
// 8 nodes/wave, 16 nodes/block (2 waves). Phase 2: wave 0 only.

__global__ __launch_bounds__(128, 8) void k_layer(const _Float16* __restrict__ hin,
                                                  _Float16* __restrict__ hout,
                                                  const uint2* __restrict__ hpin,
                                                  uint2* __restrict__ hpout,
                                                  const float* __restrict__ dis, const int* __restrict__ rps,
                                                  const int* __restrict__ rpe, const int* __restrict__ col,
                                                  const _Float16* __restrict__ Wp,
                                                  const float* __restrict__ bias,
                                                  const float* __restrict__ gamma,
                                                  const float* __restrict__ beta,
                                                  int store_hp) {
    __shared__ _Float16 Ls[16][136];   // 4352 B
    int tid = threadIdx.x;
    int wave = tid >> 6;
    int lane = tid & 63;
    int q = lane >> 4, l4 = lane & 15;
    int half = q & 1;
    int nbb = blockIdx.x * 16;          // block's 16 nodes (16 | NN, no tail)
    int nbase = nbb + wave * 8;         // this wave's 8 nodes

    // wave-wide prefetch of the 8 nodes' CSR ranges + dis
    int l8 = lane & 7;
    int ev0 = rps[nbase + l8];
    int ev1 = rpe[nbase + l8];
    float dv = dis[nbase + l8];

    // ---- phase 1: gather 8 nodes, 2 per round; quarter-pair splits edges ----
#pragma unroll 1
    for (int r = 0; r < 4; r++) {
        int nl = r * 2 + (q >> 1);      // node slot 0..7 within wave
        int e0 = __shfl(ev0, nl, 64);
        int e1 = __shfl(ev1, nl, 64);
        float dn = __shfl(dv, nl, 64);
        int node = nbase + nl;

        f32x2 a2[4];
#pragma unroll
        for (int j = 0; j < 4; j++) a2[j] = (f32x2){0.f, 0.f};

        uint2 sv;
        if (half) sv = hpin[(size_t)node * 16 + l4];   // self row on odd half

        int e = e0 + half;              // odd/even interleave
#pragma unroll 1
        for (; e + 6 < e1; e += 8) {    // 4 edges per half per iter
            int s0 = col[e];
            int s1 = col[e + 2];
            int s2 = col[e + 4];
            int s3 = col[e + 6];
            uint2 v0 = hpin[(size_t)s0 * 16 + l4];
            uint2 v1 = hpin[(size_t)s1 * 16 + l4];
            uint2 v2 = hpin[(size_t)s2 * 16 + l4];
            uint2 v3 = hpin[(size_t)s3 * 16 + l4];
            acc_fp8x8(v0, a2);
            acc_fp8x8(v1, a2);
            acc_fp8x8(v2, a2);
            acc_fp8x8(v3, a2);
        }
#pragma unroll 1
        for (; e < e1; e += 2) {
            int s = col[e];
            uint2 v = hpin[(size_t)s * 16 + l4];
            acc_fp8x8(v, a2);
        }
        if (half) acc_fp8x8(sv, a2);    // self-loop once per node

        // combine the two halves (q0<->q1, q2<->q3)
#pragma unroll
        for (int j = 0; j < 4; j++) {
            float x0 = a2[j][0], x1 = a2[j][1];
            x0 += __shfl_xor(x0, 16, 64);
            x1 += __shfl_xor(x1, 16, 64);
            a2[j][0] = x0; a2[j][1] = x1;
        }
        if (!half) {
            f16x8 o;
#pragma unroll
            for (int j = 0; j < 4; j++) {
                o[2 * j]     = (_Float16)(a2[j][0] * dn);
                o[2 * j + 1] = (_Float16)(a2[j][1] * dn);
            }
            *(f16x8*)&Ls[wave * 8 + nl][l4 * 8] = o;
        }
    }

    __syncthreads();
    if (wave == 1) return;   // no further barriers; wave 0 finishes the block

    // ---- phase 2: read A-fragments into registers, then GEMM + LN (Ls reused) ----
    f16x8 af[4];
#pragma unroll
    for (int ks = 0; ks < 4; ks++)
        af[ks] = *(const f16x8*)&Ls[l4][ks * 32 + q * 8];

    float bb[8], gm[8], bt[8];
#pragma unroll
    for (int nt = 0; nt < 8; nt++) {
        bb[nt] = bias[nt * 16 + l4];
        gm[nt] = gamma[nt * 16 + l4];
        bt[nt] = beta[nt * 16 + l4];
    }

    const f16x8* wp8 = (const f16x8*)Wp;
    f32x4 acc[8];
#pragma unroll
    for (int nt = 0; nt < 8; nt++) {
        acc[nt] = (f32x4){0.f, 0.f, 0.f, 0.f};
#pragma unroll
        for (int ks = 0; ks < 4; ks++) {
            f16x8 bf = wp8[(ks * 8 + nt) * 64 + lane];
            acc[nt] = __builtin_amdgcn_mfma_f32_16x16x32_f16(af[ks], bf, acc[nt], 0, 0, 0);
        }
#pragma unroll
        for (int r = 0; r < 4; r++) acc[nt][r] += bb[nt];
    }

    float mu[4], rs[4];
#pragma unroll
    for (int r = 0; r < 4; r++) {
        float s = 0.f;
#pragma unroll
        for (int nt = 0; nt < 8; nt++) s += acc[nt][r];
#pragma unroll
        for (int off = 8; off > 0; off >>= 1) s += __shfl_xor(s, off, 64);
        mu[r] = s * (1.f / 128.f);
    }
#pragma unroll
    for (int r = 0; r < 4; r++) {
        float v = 0.f;
#pragma unroll
        for (int nt = 0; nt < 8; nt++) {
            float d = acc[nt][r] - mu[r];
            v += d * d;
        }
#pragma unroll
        for (int off = 8; off > 0; off >>= 1) v += __shfl_xor(v, off, 64);
        rs[r] = rsqrtf(v * (1.f / 128.f) + EPS);
    }

    // overwrite Ls with LN output (af already in registers)
#pragma unroll
    for (int nt = 0; nt < 8; nt++)
#pragma unroll
        for (int r = 0; r < 4; r++) {
            float o = fmaxf((acc[nt][r] - mu[r]) * rs[r] * gm[nt] + bt[nt], 0.f);
            Ls[q * 4 + r][nt * 16 + l4] = (_Float16)o;
        }

    // epilogue: residual add (hin) + coalesced store to hout + fp8 gather copy
    float dve = dis[nbb + (lane & 15)];
    const f16x8* hi8 = (const f16x8*)hin;
    f16x8* ho8 = (f16x8*)hout;
#pragma unroll
    for (int it = 0; it < 4; it++) {
        int c = it * 64 + lane;
        int rr = c >> 4, ck = c & 15;   // rr = it*4 + q
        int row = nbb + rr;
        f16x8 ln = *(const f16x8*)&Ls[rr][ck * 8];
        f16x8 res = hi8[(size_t)row * 16 + ck];
        float dn2 = __shfl(dve, rr, 64);
        f16x8 o;
        float hv[8];
#pragma unroll
        for (int j = 0; j < 8; j++) {
            float s = (float)ln[j] + (float)res[j];
            o[j] = (_Float16)s;
            hv[j] = s * dn2;
        }
        ho8[(size_t)row * 16 + ck] = o;
        if (store_hp)
            hpout[(size_t)row * 16 + ck] = pack_fp8x8(hv);
    }
}

// ---------------- pooling ----------------

__global__ void k_range(const int* __restrict__ batch, int* __restrict__ gstart, int* __restrict__ gend) {
    int n = blockIdx.x * 256 + threadIdx.x;
    if (n < NN) {
        int g = batch[n];
        atomicMin(&gstart[g], n);
        atomicMax(&gend[g], n + 1);
    }
}

// One wave per graph; lane = (node slot p4, col group l4); f16x8 loads, 4 nodes/iter.
__global__ __launch_bounds__(256) void k_pool(const _Float16* __restrict__ hh, const int* __restrict__ gstart,
                                              const int* __restrict__ gend, const float* __restrict__ Wout,
                                              const float* __restrict__ bout, float* __restrict__ out) {
    int tid = threadIdx.x;
    int lane = tid & 63;
    int p4 = lane >> 4;     // node slot 0..3
    int l4 = lane & 15;     // cols l4*8 .. +7
    int g = blockIdx.x * 4 + (tid >> 6);
    if (g >= NG) return;

    int s = gstart[g], e = gend[g];
    const f16x8* h8 = (const f16x8*)hh;
    float acc[8];
#pragma unroll
    for (int j = 0; j < 8; j++) acc[j] = 0.f;
    for (int n = s + p4; n < e; n += 4) {
        f16x8 v = h8[(size_t)n * 16 + l4];
#pragma unroll
        for (int j = 0; j < 8; j++) acc[j] += (float)v[j];
    }
    // combine node slots
#pragma unroll
    for (int j = 0; j < 8; j++) {
        acc[j] += __shfl_xor(acc[j], 16, 64);
        acc[j] += __shfl_xor(acc[j], 32, 64);
    }
    float p = 0.f;
#pragma unroll
    for (int j = 0; j < 8; j++) p += acc[j] * Wout[l4 * 8 + j];
    // reduce across the 16 col groups
#pragma unroll
    for (int off = 8; off > 0; off >>= 1) p += __shfl_xor(p, off, 64);
    if (lane == 0) {
        float inv = 1.f / (float)max(e - s, 1);
        out[g] = p * inv + bout[0];
    }
}

// ---------------- launcher ----------------

extern "C" void kernel_launch(void* const* d_in, const int* in_sizes, int n_in,
                              void* d_out, int out_size, void* d_ws, size_t ws_size,
                              hipStream_t stream) {
    const float* x       = (const float*)d_in[0];
    const int*   edge    = (const int*)d_in[1];
    const int*   batch   = (const int*)d_in[2];
    const float* W_embed = (const float*)d_in[3];
    const float* b_embed = (const float*)d_in[4];
    const float* W_gnn   = (const float*)d_in[5];
    const float* b_gnn   = (const float*)d_in[6];
    const float* gamma   = (const float*)d_in[7];
    const float* beta    = (const float*)d_in[8];
    const float* W_out   = (const float*)d_in[9];
    const float* b_out   = (const float*)d_in[10];
    float* out = (float*)d_out;

    char* ws = (char*)d_ws;
    size_t off = 0;
    auto alloc = [&](size_t bytes) -> char* {
        char* p = ws + off;
        off += (bytes + 255) & ~(size_t)255;
        return p;
    };
    _Float16*     hh0  = (_Float16*)alloc((size_t)NN * H * 2);
    _Float16*     hh1  = (_Float16*)alloc((size_t)NN * H * 2);
    uint2*        hp0  = (uint2*)alloc((size_t)NN * H);       // fp8 gather copies
    uint2*        hp1  = (uint2*)alloc((size_t)NN * H);
    _Float16*     Wp   = (_Float16*)alloc((size_t)NL * 4 * 8 * 512 * 2);
    float*        dis  = (float*)alloc((size_t)NN * 4);
    int*          rps  = (int*)alloc((size_t)NN * 4);
    int*          rpe  = (int*)alloc((size_t)NN * 4);
    int*          col  = (int*)alloc((size_t)NBKT * CAP * 4);
    unsigned int* ebuf = (unsigned int*)alloc((size_t)NBKT * CAP * 4);
    int*          bfill = (int*)alloc((NBKT + 1) * 4);
    int*   gstart = (int*)alloc((size_t)NG * 4);
    int*   gend   = (int*)alloc((size_t)NG * 4);

    const int* srcp = edge;
    const int* dstp = edge + NE;

    k_init<<<(NG + 255) / 256, 256, 0, stream>>>(bfill, gstart, gend);
    k_bscatter<<<NBB, 256, 0, stream>>>(srcp, dstp, bfill, ebuf);
    k_bcsr<<<NBKT, 256, 0, stream>>>(ebuf, bfill, rps, rpe, col, dis);

    k_wpack<<<32, 256, 0, stream>>>(W_gnn, Wp);
    k_embed<<<NN / 16, 256, 0, stream>>>(x, W_embed, b_embed, hh0, dis, hp0);

    // ping-pong: L0 hh0->hh1, L1 hh1->hh0, L2 hh0->hh1, L3 hh1->hh0
    _Float16* hb[2] = {hh0, hh1};
    uint2*    hp[2] = {hp0, hp1};
    for (int l = 0; l < NL; l++) {
        k_layer<<<NN / 16, 128, 0, stream>>>(hb[l & 1], hb[(l & 1) ^ 1],
                                             hp[l & 1], hp[(l & 1) ^ 1],
                                             dis, rps, rpe, col,
                                             Wp + (size_t)l * 4 * 8 * 512,
                                             b_gnn + l * H, gamma + l * H, beta + l * H,
                                             (l != NL - 1) ? 1 : 0);
    }

    k_range<<<(NN + 255) / 256, 256, 0, stream>>>(batch, gstart, gend);
    k_pool<<<NG / 4, 256, 0, stream>>>(hh0, gstart, gend, W_out, b_out, out);
}

// Round 8
// 366.494 us; speedup vs baseline: 1.2194x; 1.1034x over previous
//
#include <hip/hip_runtime.h>

#define NN 100000
#define NE 1600000
#define DIM0 11
#define H 128
#define NL 4
#define NG 4096
#define EPS 1e-5f

#define NBKT 391       // buckets of 256 nodes: bucket = dst >> 8
#define CAP 5120       // fixed bucket capacity (mean 4096, sigma 64 -> 16 sigma)
#define EPB 2048       // edges per block in scatter phase
static constexpr int NBB = (NE + EPB - 1) / EPB;  // 782

typedef _Float16 f16x8 __attribute__((ext_vector_type(8)));
typedef _Float16 f16x2 __attribute__((ext_vector_type(2)));
typedef float f32x4 __attribute__((ext_vector_type(4)));
typedef float f32x2 __attribute__((ext_vector_type(2)));

// r20 resubmission (r7 container failure diagnosed as infra flake: all
// prefetch indices clamped in-bounds, loops strictly terminate, same launch
// shapes; r2 precedent -- identical resubmit passed). If THIS fails too,
// col-prefetch is convicted by elimination -> revert to r16 engine next.
// Engine: r16 shape (no barriers, wave-independent, 16 nodes/wave,
// quarter-per-node, depth-4 rows) + col-index-only software pipeline (next
// iter's 4 cols prefetched during current row loads; row window unchanged --
// r17 proved widening the row window inflates FETCH +16%).

// ---- fp8 helpers (OCP e4m3 on gfx950) ----

__device__ __forceinline__ uint2 pack_fp8x8(const float* v) {
    int lo = 0, hi = 0;
    lo = __builtin_amdgcn_cvt_pk_fp8_f32(v[0], v[1], lo, false);
    lo = __builtin_amdgcn_cvt_pk_fp8_f32(v[2], v[3], lo, true);
    hi = __builtin_amdgcn_cvt_pk_fp8_f32(v[4], v[5], hi, false);
    hi = __builtin_amdgcn_cvt_pk_fp8_f32(v[6], v[7], hi, true);
    return (uint2){(unsigned)lo, (unsigned)hi};
}

__device__ __forceinline__ void acc_fp8x8(uint2 u, f32x2* a2) {
    a2[0] += __builtin_amdgcn_cvt_pk_f32_fp8((int)u.x, false);
    a2[1] += __builtin_amdgcn_cvt_pk_f32_fp8((int)u.x, true);
    a2[2] += __builtin_amdgcn_cvt_pk_f32_fp8((int)u.y, false);
    a2[3] += __builtin_amdgcn_cvt_pk_f32_fp8((int)u.y, true);
}

// ---------------- init ----------------

__global__ void k_init(int* __restrict__ bfill, int* __restrict__ gstart, int* __restrict__ gend) {
    int i = blockIdx.x * 256 + threadIdx.x;
    if (i <= NBKT) bfill[i] = 0;
    if (i < NG) { gstart[i] = 0x7fffffff; gend[i] = 0; }
}

// ---------------- bucketed CSR build ----------------

__global__ __launch_bounds__(256) void k_bscatter(const int* __restrict__ src, const int* __restrict__ dst,
                                                  int* __restrict__ bfill, unsigned int* __restrict__ ebuf) {
    __shared__ int lc[NBKT];
    __shared__ int lbase[NBKT];
    int t = threadIdx.x;
    for (int i = t; i < NBKT; i += 256) lc[i] = 0;
    __syncthreads();
    int base = blockIdx.x * EPB;
    int rank[8];
    int bk[8];
    unsigned pk[8];
#pragma unroll
    for (int i = 0; i < 8; i++) {
        int e = base + i * 256 + t;
        if (e < NE) {
            int d = dst[e];
            int s = src[e];
            int b = d >> 8;
            bk[i] = b;
            pk[i] = (unsigned)s | ((unsigned)(d & 255) << 17);
            rank[i] = atomicAdd(&lc[b], 1);
        } else bk[i] = -1;
    }
    __syncthreads();
    for (int i = t; i < NBKT; i += 256)
        lbase[i] = i * CAP + (lc[i] ? atomicAdd(&bfill[i], lc[i]) : 0);
    __syncthreads();
#pragma unroll
    for (int i = 0; i < 8; i++) {
        if (bk[i] >= 0)
            ebuf[lbase[bk[i]] + rank[i]] = pk[i];
    }
}

// One block per bucket (391 blocks): count -> dis, scan -> rps/rpe, scatter -> col.
__global__ __launch_bounds__(256) void k_bcsr(const unsigned int* __restrict__ ebuf,
                                              const int* __restrict__ bfill,
                                              int* __restrict__ rps, int* __restrict__ rpe,
                                              int* __restrict__ col, float* __restrict__ dis) {
    __shared__ int lcnt[256];
    __shared__ int lfill[256];
    __shared__ int tmp[256];
    int t = threadIdx.x;
    int b = blockIdx.x;
    int cb = b * CAP;
    int ecnt = bfill[b];
    int n0 = b << 8;
    int nb = min(256, NN - n0);

    lcnt[t] = 0;
    lfill[t] = 0;
    __syncthreads();

    for (int i = t; i < ecnt; i += 256) {
        unsigned p = ebuf[cb + i];
        atomicAdd(&lcnt[p >> 17], 1);
    }
    __syncthreads();

    if (t < nb) dis[n0 + t] = rsqrtf((float)(lcnt[t] + 1));

    int v = lcnt[t];
    tmp[t] = v;
    __syncthreads();
    for (int off = 1; off < 256; off <<= 1) {
        int x = (t >= off) ? tmp[t - off] : 0;
        __syncthreads();
        tmp[t] += x;
        __syncthreads();
    }
    lcnt[t] = tmp[t] - v;   // exclusive scan
    __syncthreads();

    if (t < nb) {
        rps[n0 + t] = cb + lcnt[t];
        rpe[n0 + t] = cb + ((t < 255) ? lcnt[t + 1] : ecnt);
    }

    for (int i = t; i < ecnt; i += 256) {
        unsigned p = ebuf[cb + i];
        int dl = p >> 17;
        int s = (int)(p & 0x1FFFFu);
        col[cb + lcnt[dl] + atomicAdd(&lfill[dl], 1)] = s;
    }
}

// ---------------- embed: hh = fp16(relu(x @ W_embed + b)); hp = fp8(hh * dis) ----------------

__global__ __launch_bounds__(256) void k_embed(const float* __restrict__ x, const float* __restrict__ W,
                                               const float* __restrict__ b, _Float16* __restrict__ hh,
                                               const float* __restrict__ dis, uint2* __restrict__ hp) {
    __shared__ float Ws[DIM0 * H];
    __shared__ float bs[H];
    __shared__ float xs[16 * DIM0];
    int tid = threadIdx.x;
    for (int i = tid; i < DIM0 * H; i += 256) Ws[i] = W[i];
    if (tid < H) bs[tid] = b[tid];
    if (tid < 16 * DIM0) xs[tid] = x[(size_t)blockIdx.x * (16 * DIM0) + tid];
    __syncthreads();
    int nl = tid >> 4;
    int node = blockIdx.x * 16 + nl;
    int l4 = tid & 15;
    float dn = dis[node];
    f16x8 o;
    float hv[8];
#pragma unroll
    for (int j = 0; j < 8; j++) {
        int c = l4 * 8 + j;
        float acc = bs[c];
#pragma unroll
        for (int k = 0; k < DIM0; k++) acc += xs[nl * DIM0 + k] * Ws[k * H + c];
        float r = fmaxf(acc, 0.f);
        o[j] = (_Float16)r;
        hv[j] = r * dn;
    }
    *(f16x8*)&hh[(size_t)node * H + l4 * 8] = o;
    hp[(size_t)node * 16 + l4] = pack_fp8x8(hv);
}

// ---------------- W pack: W[l][k][n] fp32 -> B-fragment-layout fp16 ----------------

__global__ __launch_bounds__(256) void k_wpack(const float* __restrict__ W, _Float16* __restrict__ Wp) {
    int t = blockIdx.x * 256 + threadIdx.x;   // 8192 threads
    int lane = t & 63;
    int idx = t >> 6;          // 0..127
    int nt = idx & 7;
    int ks = (idx >> 3) & 3;
    int l = idx >> 5;
    int q = lane >> 4, l15 = lane & 15;
    const float* Wl = W + (size_t)l * H * H;
    _Float16* o = Wp + (size_t)idx * 512 + lane * 8;
#pragma unroll
    for (int j = 0; j < 8; j++)
        o[j] = (_Float16)(Wl[(ks * 32 + q * 8 + j) * H + nt * 16 + l15]);
}

// ---------------- fused layer: hout = relu(LN(agg(hin) @ W + b)) + hin ----------------
// r16 engine: 4 rounds x 4 nodes; each 16-lane quarter owns one node; waves
// fully independent (no barriers). r20: col-index-only prefetch pipeline.

__global__ __launch_bounds__(128, 8) void k_layer(const _Float16* __restrict__ hin,
                                                  _Float16* __restrict__ hout,
                                                  const uint2* __restrict__ hpin,
                                                  uint2* __restrict__ hpout,
                                                  const float* __restrict__ dis, const int* __restrict__ rps,
                                                  const int* __restrict__ rpe, const int* __restrict__ col,
                                                  const _Float16* __restrict__ Wp,
                                                  const float* __restrict__ bias,
                                                  const float* __restrict__ gamma,
                                                  const float* __restrict__ beta,
                                                  int store_hp) {
    __shared__ _Float16 Ls[2][16][136];   // 8704 B
    int tid = threadIdx.x;
    int wave = tid >> 6;
    int lane = tid & 63;
    int q = lane >> 4, l4 = lane & 15;
    int nbase = blockIdx.x * 32 + wave * 16;   // 32 | NN, no tail

    // wave-wide prefetch of the 16 nodes' CSR ranges + dis
    int l16 = lane & 15;
    int ev0 = rps[nbase + l16];
    int ev1 = rpe[nbase + l16];
    float dv = dis[nbase + l16];

    // ---- phase 1: gather 16 nodes into Ls, 4 nodes per round ----
#pragma unroll 1
    for (int r = 0; r < 4; r++) {
        int nl = r * 4 + q;                 // node slot owned by this quarter
        int e0 = __shfl(ev0, nl, 64);
        int e1 = __shfl(ev1, nl, 64);
        float dn = __shfl(dv, nl, 64);
        int node = nbase + nl;

        f32x2 a2[4];
#pragma unroll
        for (int j = 0; j < 4; j++) a2[j] = (f32x2){0.f, 0.f};

        uint2 sv = hpin[(size_t)node * 16 + l4];   // self row, issued early

        int e = e0;
        int pc0 = 0, pc1 = 0, pc2 = 0, pc3 = 0;
        if (e < e1) {                       // prime col pipeline (clamped)
            int m = e1 - 1;
            pc0 = col[e];
            pc1 = col[(e + 1 < e1) ? e + 1 : m];
            pc2 = col[(e + 2 < e1) ? e + 2 : m];
            pc3 = col[(e + 3 < e1) ? e + 3 : m];
        }
#pragma unroll 1
        for (; e + 3 < e1; e += 4) {
            int s0 = pc0, s1 = pc1, s2 = pc2, s3 = pc3;
            int n0 = e + 4, n1 = e + 5, n2 = e + 6, n3 = e + 7;
            pc0 = col[(n0 < e1) ? n0 : e0];   // next-iter cols overlap row loads
            pc1 = col[(n1 < e1) ? n1 : e0];
            pc2 = col[(n2 < e1) ? n2 : e0];
            pc3 = col[(n3 < e1) ? n3 : e0];
            uint2 v0 = hpin[(size_t)s0 * 16 + l4];
            uint2 v1 = hpin[(size_t)s1 * 16 + l4];
            uint2 v2 = hpin[(size_t)s2 * 16 + l4];
            uint2 v3 = hpin[(size_t)s3 * 16 + l4];
            acc_fp8x8(v0, a2);
            acc_fp8x8(v1, a2);
            acc_fp8x8(v2, a2);
            acc_fp8x8(v3, a2);
        }
        // tail (<=3 edges): cols already prefetched
        int k = e1 - e;
        if (k > 0) { uint2 v = hpin[(size_t)pc0 * 16 + l4]; acc_fp8x8(v, a2); }
        if (k > 1) { uint2 v = hpin[(size_t)pc1 * 16 + l4]; acc_fp8x8(v, a2); }
        if (k > 2) { uint2 v = hpin[(size_t)pc2 * 16 + l4]; acc_fp8x8(v, a2); }

        acc_fp8x8(sv, a2);   // self-loop

        f16x8 o;
#pragma unroll
        for (int j = 0; j < 4; j++) {
            o[2 * j]     = (_Float16)(a2[j][0] * dn);
            o[2 * j + 1] = (_Float16)(a2[j][1] * dn);
        }
        *(f16x8*)&Ls[wave][nl][l4 * 8] = o;
    }

    // ---- phase 2: read A-fragments into registers, then GEMM + LN (Ls reused) ----
    f16x8 af[4];
#pragma unroll
    for (int ks = 0; ks < 4; ks++)
        af[ks] = *(const f16x8*)&Ls[wave][l4][ks * 32 + q * 8];

    float bb[8], gm[8], bt[8];
#pragma unroll
    for (int nt = 0; nt < 8; nt++) {
        bb[nt] = bias[nt * 16 + l4];
        gm[nt] = gamma[nt * 16 + l4];
        bt[nt] = beta[nt * 16 + l4];
    }

    const f16x8* wp8 = (const f16x8*)Wp;
    f32x4 acc[8];
#pragma unroll
    for (int nt = 0; nt < 8; nt++) {
        acc[nt] = (f32x4){0.f, 0.f, 0.f, 0.f};
#pragma unroll
        for (int ks = 0; ks < 4; ks++) {
            f16x8 bf = wp8[(ks * 8 + nt) * 64 + lane];
            acc[nt] = __builtin_amdgcn_mfma_f32_16x16x32_f16(af[ks], bf, acc[nt], 0, 0, 0);
        }
#pragma unroll
        for (int r = 0; r < 4; r++) acc[nt][r] += bb[nt];
    }

    float mu[4], rs[4];
#pragma unroll
    for (int r = 0; r < 4; r++) {
        float s = 0.f;
#pragma unroll
        for (int nt = 0; nt < 8; nt++) s += acc[nt][r];
#pragma unroll
        for (int off = 8; off > 0; off >>= 1) s += __shfl_xor(s, off, 64);
        mu[r] = s * (1.f / 128.f);
    }
#pragma unroll
    for (int r = 0; r < 4; r++) {
        float v = 0.f;
#pragma unroll
        for (int nt = 0; nt < 8; nt++) {
            float d = acc[nt][r] - mu[r];
            v += d * d;
        }
#pragma unroll
        for (int off = 8; off > 0; off >>= 1) v += __shfl_xor(v, off, 64);
        rs[r] = rsqrtf(v * (1.f / 128.f) + EPS);
    }

    // overwrite Ls with LN output (af already in registers)
#pragma unroll
    for (int nt = 0; nt < 8; nt++)
#pragma unroll
        for (int r = 0; r < 4; r++) {
            float o = fmaxf((acc[nt][r] - mu[r]) * rs[r] * gm[nt] + bt[nt], 0.f);
            Ls[wave][q * 4 + r][nt * 16 + l4] = (_Float16)o;
        }

    // epilogue: residual add (hin) + coalesced store to hout + fp8 gather copy
    const f16x8* hi8 = (const f16x8*)hin;
    f16x8* ho8 = (f16x8*)hout;
#pragma unroll
    for (int it = 0; it < 4; it++) {
        int c = it * 64 + lane;
        int rr = c >> 4, ck = c & 15;   // rr = it*4 + q
        int row = nbase + rr;
        f16x8 ln = *(const f16x8*)&Ls[wave][rr][ck * 8];
        f16x8 res = hi8[(size_t)row * 16 + ck];
        float dn2 = __shfl(dv, rr, 64);
        f16x8 o;
        float hv[8];
#pragma unroll
        for (int j = 0; j < 8; j++) {
            float s = (float)ln[j] + (float)res[j];
            o[j] = (_Float16)s;
            hv[j] = s * dn2;
        }
        ho8[(size_t)row * 16 + ck] = o;
        if (store_hp)
            hpout[(size_t)row * 16 + ck] = pack_fp8x8(hv);
    }
}

// ---------------- pooling ----------------

__global__ void k_range(const int* __restrict__ batch, int* __restrict__ gstart, int* __restrict__ gend) {
    int n = blockIdx.x * 256 + threadIdx.x;
    if (n < NN) {
        int g = batch[n];
        atomicMin(&gstart[g], n);
        atomicMax(&gend[g], n + 1);
    }
}

// One wave per graph; lane = (node slot p4, col group l4); f16x8 loads, 4 nodes/iter.
__global__ __launch_bounds__(256) void k_pool(const _Float16* __restrict__ hh, const int* __restrict__ gstart,
                                              const int* __restrict__ gend, const float* __restrict__ Wout,
                                              const float* __restrict__ bout, float* __restrict__ out) {
    int tid = threadIdx.x;
    int lane = tid & 63;
    int p4 = lane >> 4;     // node slot 0..3
    int l4 = lane & 15;     // cols l4*8 .. +7
    int g = blockIdx.x * 4 + (tid >> 6);
    if (g >= NG) return;

    int s = gstart[g], e = gend[g];
    const f16x8* h8 = (const f16x8*)hh;
    float acc[8];
#pragma unroll
    for (int j = 0; j < 8; j++) acc[j] = 0.f;
    for (int n = s + p4; n < e; n += 4) {
        f16x8 v = h8[(size_t)n * 16 + l4];
#pragma unroll
        for (int j = 0; j < 8; j++) acc[j] += (float)v[j];
    }
    // combine node slots
#pragma unroll
    for (int j = 0; j < 8; j++) {
        acc[j] += __shfl_xor(acc[j], 16, 64);
        acc[j] += __shfl_xor(acc[j], 32, 64);
    }
    float p = 0.f;
#pragma unroll
    for (int j = 0; j < 8; j++) p += acc[j] * Wout[l4 * 8 + j];
    // reduce across the 16 col groups
#pragma unroll
    for (int off = 8; off > 0; off >>= 1) p += __shfl_xor(p, off, 64);
    if (lane == 0) {
        float inv = 1.f / (float)max(e - s, 1);
        out[g] = p * inv + bout[0];
    }
}

// ---------------- launcher ----------------

extern "C" void kernel_launch(void* const* d_in, const int* in_sizes, int n_in,
                              void* d_out, int out_size, void* d_ws, size_t ws_size,
                              hipStream_t stream) {
    const float* x       = (const float*)d_in[0];
    const int*   edge    = (const int*)d_in[1];
    const int*   batch   = (const int*)d_in[2];
    const float* W_embed = (const float*)d_in[3];
    const float* b_embed = (const float*)d_in[4];
    const float* W_gnn   = (const float*)d_in[5];
    const float* b_gnn   = (const float*)d_in[6];
    const float* gamma   = (const float*)d_in[7];
    const float* beta    = (const float*)d_in[8];
    const float* W_out   = (const float*)d_in[9];
    const float* b_out   = (const float*)d_in[10];
    float* out = (float*)d_out;

    char* ws = (char*)d_ws;
    size_t off = 0;
    auto alloc = [&](size_t bytes) -> char* {
        char* p = ws + off;
        off += (bytes + 255) & ~(size_t)255;
        return p;
    };
    _Float16*     hh0  = (_Float16*)alloc((size_t)NN * H * 2);
    _Float16*     hh1  = (_Float16*)alloc((size_t)NN * H * 2);
    uint2*        hp0  = (uint2*)alloc((size_t)NN * H);       // fp8 gather copies
    uint2*        hp1  = (uint2*)alloc((size_t)NN * H);
    _Float16*     Wp   = (_Float16*)alloc((size_t)NL * 4 * 8 * 512 * 2);
    float*        dis  = (float*)alloc((size_t)NN * 4);
    int*          rps  = (int*)alloc((size_t)NN * 4);
    int*          rpe  = (int*)alloc((size_t)NN * 4);
    int*          col  = (int*)alloc((size_t)NBKT * CAP * 4);
    unsigned int* ebuf = (unsigned int*)alloc((size_t)NBKT * CAP * 4);
    int*          bfill = (int*)alloc((NBKT + 1) * 4);
    int*   gstart = (int*)alloc((size_t)NG * 4);
    int*   gend   = (int*)alloc((size_t)NG * 4);

    const int* srcp = edge;
    const int* dstp = edge + NE;

    k_init<<<(NG + 255) / 256, 256, 0, stream>>>(bfill, gstart, gend);
    k_bscatter<<<NBB, 256, 0, stream>>>(srcp, dstp, bfill, ebuf);
    k_bcsr<<<NBKT, 256, 0, stream>>>(ebuf, bfill, rps, rpe, col, dis);

    k_wpack<<<32, 256, 0, stream>>>(W_gnn, Wp);
    k_embed<<<NN / 16, 256, 0, stream>>>(x, W_embed, b_embed, hh0, dis, hp0);

    // ping-pong: L0 hh0->hh1, L1 hh1->hh0, L2 hh0->hh1, L3 hh1->hh0
    _Float16* hb[2] = {hh0, hh1};
    uint2*    hp[2] = {hp0, hp1};
    for (int l = 0; l < NL; l++) {
        k_layer<<<(NN + 31) / 32, 128, 0, stream>>>(hb[l & 1], hb[(l & 1) ^ 1],
                                                    hp[l & 1], hp[(l & 1) ^ 1],
                                                    dis, rps, rpe, col,
                                                    Wp + (size_t)l * 4 * 8 * 512,
                                                    b_gnn + l * H, gamma + l * H, beta + l * H,
                                                    (l != NL - 1) ? 1 : 0);
    }

    k_range<<<(NN + 255) / 256, 256, 0, stream>>>(batch, gstart, gend);
    k_pool<<<NG / 4, 256, 0, stream>>>(hh0, gstart, gend, W_out, b_out, out);
}

// Round 9
// 366.413 us; speedup vs baseline: 1.2196x; 1.0002x over previous
//
#include <hip/hip_runtime.h>

#define NN 100000
#define NE 1600000
#define DIM0 11
#define H 128
#define NL 4
#define NG 4096
#define EPS 1e-5f

#define NBKT 391       // buckets of 256 nodes: bucket = dst >> 8
#define CAP 5120       // fixed bucket capacity (mean 4096, sigma 64 -> 16 sigma)
#define EPB 2048       // edges per block in scatter phase
static constexpr int NBB = (NE + EPB - 1) / EPB;  // 782

typedef _Float16 f16x8 __attribute__((ext_vector_type(8)));
typedef _Float16 f16x2 __attribute__((ext_vector_type(2)));
typedef float f32x4 __attribute__((ext_vector_type(4)));
typedef float f32x2 __attribute__((ext_vector_type(2)));

// r20 result: col-prefetch 59.5->57.2us; with ~4 loop iters/node the per-node
// PRIME bubble dominates what's left. r22 (this round):
// (a) inter-node pipeline -- during round r's accumulation, issue round r+1's
//     self row + 4 prime cols (sequential addresses, NOT a random-row window
//     widening, so r17's FETCH-inflation mechanism doesn't apply).
// (b) k_range: batch is SORTED -> boundary detection with plain stores
//     replaces 200K cross-XCD atomicMin/Max (r5 proved that mechanism costly).

// ---- fp8 helpers (OCP e4m3 on gfx950) ----

__device__ __forceinline__ uint2 pack_fp8x8(const float* v) {
    int lo = 0, hi = 0;
    lo = __builtin_amdgcn_cvt_pk_fp8_f32(v[0], v[1], lo, false);
    lo = __builtin_amdgcn_cvt_pk_fp8_f32(v[2], v[3], lo, true);
    hi = __builtin_amdgcn_cvt_pk_fp8_f32(v[4], v[5], hi, false);
    hi = __builtin_amdgcn_cvt_pk_fp8_f32(v[6], v[7], hi, true);
    return (uint2){(unsigned)lo, (unsigned)hi};
}

__device__ __forceinline__ void acc_fp8x8(uint2 u, f32x2* a2) {
    a2[0] += __builtin_amdgcn_cvt_pk_f32_fp8((int)u.x, false);
    a2[1] += __builtin_amdgcn_cvt_pk_f32_fp8((int)u.x, true);
    a2[2] += __builtin_amdgcn_cvt_pk_f32_fp8((int)u.y, false);
    a2[3] += __builtin_amdgcn_cvt_pk_f32_fp8((int)u.y, true);
}

// ---------------- init ----------------

__global__ void k_init(int* __restrict__ bfill, int* __restrict__ gstart, int* __restrict__ gend) {
    int i = blockIdx.x * 256 + threadIdx.x;
    if (i <= NBKT) bfill[i] = 0;
    if (i < NG) { gstart[i] = NN; gend[i] = 0; }
}

// ---------------- bucketed CSR build ----------------

__global__ __launch_bounds__(256) void k_bscatter(const int* __restrict__ src, const int* __restrict__ dst,
                                                  int* __restrict__ bfill, unsigned int* __restrict__ ebuf) {
    __shared__ int lc[NBKT];
    __shared__ int lbase[NBKT];
    int t = threadIdx.x;
    for (int i = t; i < NBKT; i += 256) lc[i] = 0;
    __syncthreads();
    int base = blockIdx.x * EPB;
    int rank[8];
    int bk[8];
    unsigned pk[8];
#pragma unroll
    for (int i = 0; i < 8; i++) {
        int e = base + i * 256 + t;
        if (e < NE) {
            int d = dst[e];
            int s = src[e];
            int b = d >> 8;
            bk[i] = b;
            pk[i] = (unsigned)s | ((unsigned)(d & 255) << 17);
            rank[i] = atomicAdd(&lc[b], 1);
        } else bk[i] = -1;
    }
    __syncthreads();
    for (int i = t; i < NBKT; i += 256)
        lbase[i] = i * CAP + (lc[i] ? atomicAdd(&bfill[i], lc[i]) : 0);
    __syncthreads();
#pragma unroll
    for (int i = 0; i < 8; i++) {
        if (bk[i] >= 0)
            ebuf[lbase[bk[i]] + rank[i]] = pk[i];
    }
}

// One block per bucket (391 blocks): count -> dis, scan -> rps/rpe, scatter -> col.
__global__ __launch_bounds__(256) void k_bcsr(const unsigned int* __restrict__ ebuf,
                                              const int* __restrict__ bfill,
                                              int* __restrict__ rps, int* __restrict__ rpe,
                                              int* __restrict__ col, float* __restrict__ dis) {
    __shared__ int lcnt[256];
    __shared__ int lfill[256];
    __shared__ int tmp[256];
    int t = threadIdx.x;
    int b = blockIdx.x;
    int cb = b * CAP;
    int ecnt = bfill[b];
    int n0 = b << 8;
    int nb = min(256, NN - n0);

    lcnt[t] = 0;
    lfill[t] = 0;
    __syncthreads();

    for (int i = t; i < ecnt; i += 256) {
        unsigned p = ebuf[cb + i];
        atomicAdd(&lcnt[p >> 17], 1);
    }
    __syncthreads();

    if (t < nb) dis[n0 + t] = rsqrtf((float)(lcnt[t] + 1));

    int v = lcnt[t];
    tmp[t] = v;
    __syncthreads();
    for (int off = 1; off < 256; off <<= 1) {
        int x = (t >= off) ? tmp[t - off] : 0;
        __syncthreads();
        tmp[t] += x;
        __syncthreads();
    }
    lcnt[t] = tmp[t] - v;   // exclusive scan
    __syncthreads();

    if (t < nb) {
        rps[n0 + t] = cb + lcnt[t];
        rpe[n0 + t] = cb + ((t < 255) ? lcnt[t + 1] : ecnt);
    }

    for (int i = t; i < ecnt; i += 256) {
        unsigned p = ebuf[cb + i];
        int dl = p >> 17;
        int s = (int)(p & 0x1FFFFu);
        col[cb + lcnt[dl] + atomicAdd(&lfill[dl], 1)] = s;
    }
}

// ---------------- embed: hh = fp16(relu(x @ W_embed + b)); hp = fp8(hh * dis) ----------------

__global__ __launch_bounds__(256) void k_embed(const float* __restrict__ x, const float* __restrict__ W,
                                               const float* __restrict__ b, _Float16* __restrict__ hh,
                                               const float* __restrict__ dis, uint2* __restrict__ hp) {
    __shared__ float Ws[DIM0 * H];
    __shared__ float bs[H];
    __shared__ float xs[16 * DIM0];
    int tid = threadIdx.x;
    for (int i = tid; i < DIM0 * H; i += 256) Ws[i] = W[i];
    if (tid < H) bs[tid] = b[tid];
    if (tid < 16 * DIM0) xs[tid] = x[(size_t)blockIdx.x * (16 * DIM0) + tid];
    __syncthreads();
    int nl = tid >> 4;
    int node = blockIdx.x * 16 + nl;
    int l4 = tid & 15;
    float dn = dis[node];
    f16x8 o;
    float hv[8];
#pragma unroll
    for (int j = 0; j < 8; j++) {
        int c = l4 * 8 + j;
        float acc = bs[c];
#pragma unroll
        for (int k = 0; k < DIM0; k++) acc += xs[nl * DIM0 + k] * Ws[k * H + c];
        float r = fmaxf(acc, 0.f);
        o[j] = (_Float16)r;
        hv[j] = r * dn;
    }
    *(f16x8*)&hh[(size_t)node * H + l4 * 8] = o;
    hp[(size_t)node * 16 + l4] = pack_fp8x8(hv);
}

// ---------------- W pack: W[l][k][n] fp32 -> B-fragment-layout fp16 ----------------

__global__ __launch_bounds__(256) void k_wpack(const float* __restrict__ W, _Float16* __restrict__ Wp) {
    int t = blockIdx.x * 256 + threadIdx.x;   // 8192 threads
    int lane = t & 63;
    int idx = t >> 6;          // 0..127
    int nt = idx & 7;
    int ks = (idx >> 3) & 3;
    int l = idx >> 5;
    int q = lane >> 4, l15 = lane & 15;
    const float* Wl = W + (size_t)l * H * H;
    _Float16* o = Wp + (size_t)idx * 512 + lane * 8;
#pragma unroll
    for (int j = 0; j < 8; j++)
        o[j] = (_Float16)(Wl[(ks * 32 + q * 8 + j) * H + nt * 16 + l15]);
}

// ---------------- fused layer: hout = relu(LN(agg(hin) @ W + b)) + hin ----------------
// r16 engine + r20 col pipeline + r22 inter-node pipeline: next round's self
// row + prime cols issued before the current round's accumulation loop.

__global__ __launch_bounds__(128, 8) void k_layer(const _Float16* __restrict__ hin,
                                                  _Float16* __restrict__ hout,
                                                  const uint2* __restrict__ hpin,
                                                  uint2* __restrict__ hpout,
                                                  const float* __restrict__ dis, const int* __restrict__ rps,
                                                  const int* __restrict__ rpe, const int* __restrict__ col,
                                                  const _Float16* __restrict__ Wp,
                                                  const float* __restrict__ bias,
                                                  const float* __restrict__ gamma,
                                                  const float* __restrict__ beta,
                                                  int store_hp) {
    __shared__ _Float16 Ls[2][16][136];   // 8704 B
    int tid = threadIdx.x;
    int wave = tid >> 6;
    int lane = tid & 63;
    int q = lane >> 4, l4 = lane & 15;
    int nbase = blockIdx.x * 32 + wave * 16;   // 32 | NN, no tail

    // wave-wide prefetch of the 16 nodes' CSR ranges + dis
    int l16 = lane & 15;
    int ev0 = rps[nbase + l16];
    int ev1 = rpe[nbase + l16];
    float dv = dis[nbase + l16];

    // ---- phase 1: gather 16 nodes into Ls, 4 nodes per round ----
    // pipeline state for the CURRENT round
    int e0c = __shfl(ev0, q, 64);
    int e1c = __shfl(ev1, q, 64);
    float dnc = __shfl(dv, q, 64);
    uint2 svc = hpin[(size_t)(nbase + q) * 16 + l4];
    int pc0 = 0, pc1 = 0, pc2 = 0, pc3 = 0;
    if (e0c < e1c) {
        int m = e1c - 1;
        pc0 = col[e0c];
        pc1 = col[(e0c + 1 < e1c) ? e0c + 1 : m];
        pc2 = col[(e0c + 2 < e1c) ? e0c + 2 : m];
        pc3 = col[(e0c + 3 < e1c) ? e0c + 3 : m];
    }

#pragma unroll 1
    for (int r = 0; r < 4; r++) {
        int nl = r * 4 + q;                 // node slot owned by this quarter

        // issue NEXT round's self row + prime cols before accumulating
        int e0n = 0, e1n = 0;
        float dnn = 0.f;
        uint2 svn = (uint2){0u, 0u};
        int qn0 = 0, qn1 = 0, qn2 = 0, qn3 = 0;
        if (r < 3) {
            e0n = __shfl(ev0, nl + 4, 64);
            e1n = __shfl(ev1, nl + 4, 64);
            dnn = __shfl(dv, nl + 4, 64);
            svn = hpin[(size_t)(nbase + nl + 4) * 16 + l4];
            if (e0n < e1n) {
                int m = e1n - 1;
                qn0 = col[e0n];
                qn1 = col[(e0n + 1 < e1n) ? e0n + 1 : m];
                qn2 = col[(e0n + 2 < e1n) ? e0n + 2 : m];
                qn3 = col[(e0n + 3 < e1n) ? e0n + 3 : m];
            }
        }

        f32x2 a2[4];
#pragma unroll
        for (int j = 0; j < 4; j++) a2[j] = (f32x2){0.f, 0.f};

        int e = e0c;
        int e1 = e1c;
#pragma unroll 1
        for (; e + 3 < e1; e += 4) {
            int s0 = pc0, s1 = pc1, s2 = pc2, s3 = pc3;
            int n0 = e + 4, n1 = e + 5, n2 = e + 6, n3 = e + 7;
            pc0 = col[(n0 < e1) ? n0 : e0c];   // next-iter cols overlap row loads
            pc1 = col[(n1 < e1) ? n1 : e0c];
            pc2 = col[(n2 < e1) ? n2 : e0c];
            pc3 = col[(n3 < e1) ? n3 : e0c];
            uint2 v0 = hpin[(size_t)s0 * 16 + l4];
            uint2 v1 = hpin[(size_t)s1 * 16 + l4];
            uint2 v2 = hpin[(size_t)s2 * 16 + l4];
            uint2 v3 = hpin[(size_t)s3 * 16 + l4];
            acc_fp8x8(v0, a2);
            acc_fp8x8(v1, a2);
            acc_fp8x8(v2, a2);
            acc_fp8x8(v3, a2);
        }
        // tail (<=3 edges): cols already prefetched
        int k = e1 - e;
        if (k > 0) { uint2 v = hpin[(size_t)pc0 * 16 + l4]; acc_fp8x8(v, a2); }
        if (k > 1) { uint2 v = hpin[(size_t)pc1 * 16 + l4]; acc_fp8x8(v, a2); }
        if (k > 2) { uint2 v = hpin[(size_t)pc2 * 16 + l4]; acc_fp8x8(v, a2); }

        acc_fp8x8(svc, a2);   // self-loop

        f16x8 o;
#pragma unroll
        for (int j = 0; j < 4; j++) {
            o[2 * j]     = (_Float16)(a2[j][0] * dnc);
            o[2 * j + 1] = (_Float16)(a2[j][1] * dnc);
        }
        *(f16x8*)&Ls[wave][nl][l4 * 8] = o;

        // rotate pipeline state
        e0c = e0n; e1c = e1n; dnc = dnn; svc = svn;
        pc0 = qn0; pc1 = qn1; pc2 = qn2; pc3 = qn3;
    }

    // ---- phase 2: read A-fragments into registers, then GEMM + LN (Ls reused) ----
    f16x8 af[4];
#pragma unroll
    for (int ks = 0; ks < 4; ks++)
        af[ks] = *(const f16x8*)&Ls[wave][l4][ks * 32 + q * 8];

    float bb[8], gm[8], bt[8];
#pragma unroll
    for (int nt = 0; nt < 8; nt++) {
        bb[nt] = bias[nt * 16 + l4];
        gm[nt] = gamma[nt * 16 + l4];
        bt[nt] = beta[nt * 16 + l4];
    }

    const f16x8* wp8 = (const f16x8*)Wp;
    f32x4 acc[8];
#pragma unroll
    for (int nt = 0; nt < 8; nt++) {
        acc[nt] = (f32x4){0.f, 0.f, 0.f, 0.f};
#pragma unroll
        for (int ks = 0; ks < 4; ks++) {
            f16x8 bf = wp8[(ks * 8 + nt) * 64 + lane];
            acc[nt] = __builtin_amdgcn_mfma_f32_16x16x32_f16(af[ks], bf, acc[nt], 0, 0, 0);
        }
#pragma unroll
        for (int r = 0; r < 4; r++) acc[nt][r] += bb[nt];
    }

    float mu[4], rs[4];
#pragma unroll
    for (int r = 0; r < 4; r++) {
        float s = 0.f;
#pragma unroll
        for (int nt = 0; nt < 8; nt++) s += acc[nt][r];
#pragma unroll
        for (int off = 8; off > 0; off >>= 1) s += __shfl_xor(s, off, 64);
        mu[r] = s * (1.f / 128.f);
    }
#pragma unroll
    for (int r = 0; r < 4; r++) {
        float v = 0.f;
#pragma unroll
        for (int nt = 0; nt < 8; nt++) {
            float d = acc[nt][r] - mu[r];
            v += d * d;
        }
#pragma unroll
        for (int off = 8; off > 0; off >>= 1) v += __shfl_xor(v, off, 64);
        rs[r] = rsqrtf(v * (1.f / 128.f) + EPS);
    }

    // overwrite Ls with LN output (af already in registers)
#pragma unroll
    for (int nt = 0; nt < 8; nt++)
#pragma unroll
        for (int r = 0; r < 4; r++) {
            float o = fmaxf((acc[nt][r] - mu[r]) * rs[r] * gm[nt] + bt[nt], 0.f);
            Ls[wave][q * 4 + r][nt * 16 + l4] = (_Float16)o;
        }

    // epilogue: residual add (hin) + coalesced store to hout + fp8 gather copy
    const f16x8* hi8 = (const f16x8*)hin;
    f16x8* ho8 = (f16x8*)hout;
#pragma unroll
    for (int it = 0; it < 4; it++) {
        int c = it * 64 + lane;
        int rr = c >> 4, ck = c & 15;   // rr = it*4 + q
        int row = nbase + rr;
        f16x8 ln = *(const f16x8*)&Ls[wave][rr][ck * 8];
        f16x8 res = hi8[(size_t)row * 16 + ck];
        float dn2 = __shfl(dv, rr, 64);
        f16x8 o;
        float hv[8];
#pragma unroll
        for (int j = 0; j < 8; j++) {
            float s = (float)ln[j] + (float)res[j];
            o[j] = (_Float16)s;
            hv[j] = s * dn2;
        }
        ho8[(size_t)row * 16 + ck] = o;
        if (store_hp)
            hpout[(size_t)row * 16 + ck] = pack_fp8x8(hv);
    }
}

// ---------------- pooling ----------------

// batch is sorted: graph ranges are contiguous. Boundary detection with plain
// stores; no atomics (r5 lesson: contended cross-XCD RMWs ping-pong via HBM).
__global__ void k_range(const int* __restrict__ batch, int* __restrict__ gstart, int* __restrict__ gend) {
    int n = blockIdx.x * 256 + threadIdx.x;
    if (n < NN) {
        int g = batch[n];
        if (n == 0) {
            gstart[g] = 0;
        } else {
            int gp = batch[n - 1];
            if (gp != g) { gstart[g] = n; gend[gp] = n; }
        }
        if (n == NN - 1) gend[g] = NN;
    }
}

// One wave per graph; lane = (node slot p4, col group l4); f16x8 loads, 4 nodes/iter.
__global__ __launch_bounds__(256) void k_pool(const _Float16* __restrict__ hh, const int* __restrict__ gstart,
                                              const int* __restrict__ gend, const float* __restrict__ Wout,
                                              const float* __restrict__ bout, float* __restrict__ out) {
    int tid = threadIdx.x;
    int lane = tid & 63;
    int p4 = lane >> 4;     // node slot 0..3
    int l4 = lane & 15;     // cols l4*8 .. +7
    int g = blockIdx.x * 4 + (tid >> 6);
    if (g >= NG) return;

    int s = gstart[g], e = gend[g];
    const f16x8* h8 = (const f16x8*)hh;
    float acc[8];
#pragma unroll
    for (int j = 0; j < 8; j++) acc[j] = 0.f;
    for (int n = s + p4; n < e; n += 4) {
        f16x8 v = h8[(size_t)n * 16 + l4];
#pragma unroll
        for (int j = 0; j < 8; j++) acc[j] += (float)v[j];
    }
    // combine node slots
#pragma unroll
    for (int j = 0; j < 8; j++) {
        acc[j] += __shfl_xor(acc[j], 16, 64);
        acc[j] += __shfl_xor(acc[j], 32, 64);
    }
    float p = 0.f;
#pragma unroll
    for (int j = 0; j < 8; j++) p += acc[j] * Wout[l4 * 8 + j];
    // reduce across the 16 col groups
#pragma unroll
    for (int off = 8; off > 0; off >>= 1) p += __shfl_xor(p, off, 64);
    if (lane == 0) {
        float inv = 1.f / (float)max(e - s, 1);
        out[g] = p * inv + bout[0];
    }
}

// ---------------- launcher ----------------

extern "C" void kernel_launch(void* const* d_in, const int* in_sizes, int n_in,
                              void* d_out, int out_size, void* d_ws, size_t ws_size,
                              hipStream_t stream) {
    const float* x       = (const float*)d_in[0];
    const int*   edge    = (const int*)d_in[1];
    const int*   batch   = (const int*)d_in[2];
    const float* W_embed = (const float*)d_in[3];
    const float* b_embed = (const float*)d_in[4];
    const float* W_gnn   = (const float*)d_in[5];
    const float* b_gnn   = (const float*)d_in[6];
    const float* gamma   = (const float*)d_in[7];
    const float* beta    = (const float*)d_in[8];
    const float* W_out   = (const float*)d_in[9];
    const float* b_out   = (const float*)d_in[10];
    float* out = (float*)d_out;

    char* ws = (char*)d_ws;
    size_t off = 0;
    auto alloc = [&](size_t bytes) -> char* {
        char* p = ws + off;
        off += (bytes + 255) & ~(size_t)255;
        return p;
    };
    _Float16*     hh0  = (_Float16*)alloc((size_t)NN * H * 2);
    _Float16*     hh1  = (_Float16*)alloc((size_t)NN * H * 2);
    uint2*        hp0  = (uint2*)alloc((size_t)NN * H);       // fp8 gather copies
    uint2*        hp1  = (uint2*)alloc((size_t)NN * H);
    _Float16*     Wp   = (_Float16*)alloc((size_t)NL * 4 * 8 * 512 * 2);
    float*        dis  = (float*)alloc((size_t)NN * 4);
    int*          rps  = (int*)alloc((size_t)NN * 4);
    int*          rpe  = (int*)alloc((size_t)NN * 4);
    int*          col  = (int*)alloc((size_t)NBKT * CAP * 4);
    unsigned int* ebuf = (unsigned int*)alloc((size_t)NBKT * CAP * 4);
    int*          bfill = (int*)alloc((NBKT + 1) * 4);
    int*   gstart = (int*)alloc((size_t)NG * 4);
    int*   gend   = (int*)alloc((size_t)NG * 4);

    const int* srcp = edge;
    const int* dstp = edge + NE;

    k_init<<<(NG + 255) / 256, 256, 0, stream>>>(bfill, gstart, gend);
    k_bscatter<<<NBB, 256, 0, stream>>>(srcp, dstp, bfill, ebuf);
    k_bcsr<<<NBKT, 256, 0, stream>>>(ebuf, bfill, rps, rpe, col, dis);

    k_wpack<<<32, 256, 0, stream>>>(W_gnn, Wp);
    k_embed<<<NN / 16, 256, 0, stream>>>(x, W_embed, b_embed, hh0, dis, hp0);

    // ping-pong: L0 hh0->hh1, L1 hh1->hh0, L2 hh0->hh1, L3 hh1->hh0
    _Float16* hb[2] = {hh0, hh1};
    uint2*    hp[2] = {hp0, hp1};
    for (int l = 0; l < NL; l++) {
        k_layer<<<(NN + 31) / 32, 128, 0, stream>>>(hb[l & 1], hb[(l & 1) ^ 1],
                                                    hp[l & 1], hp[(l & 1) ^ 1],
                                                    dis, rps, rpe, col,
                                                    Wp + (size_t)l * 4 * 8 * 512,
                                                    b_gnn + l * H, gamma + l * H, beta + l * H,
                                                    (l != NL - 1) ? 1 : 0);
    }

    k_range<<<(NN + 255) / 256, 256, 0, stream>>>(batch, gstart, gend);
    k_pool<<<NG / 4, 256, 0, stream>>>(hh0, gstart, gend, W_out, b_out, out);
}

// Round 10
// 360.681 us; speedup vs baseline: 1.2390x; 1.0159x over previous
//
#include <hip/hip_runtime.h>

#define NN 100000
#define NE 1600000
#define DIM0 11
#define H 128
#define NL 4
#define NG 4096
#define EPS 1e-5f

#define NBKT 391       // buckets of 256 nodes: bucket = dst >> 8
#define CAP 5120       // fixed bucket capacity (mean 4096, sigma 64 -> 16 sigma)
#define EPB 2048       // edges per block in scatter phase
static constexpr int NBB = (NE + EPB - 1) / EPB;  // 782

typedef _Float16 f16x8 __attribute__((ext_vector_type(8)));
typedef _Float16 f16x2 __attribute__((ext_vector_type(2)));
typedef float f32x4 __attribute__((ext_vector_type(4)));
typedef float f32x2 __attribute__((ext_vector_type(2)));

// r22 post-mortem: inter-node pipeline widened the random live window ->
// FETCH 103.6->108.1, dur 57.2->59.7. Third confirmation of the window rule
// (r17/r18/r22). Phase 1 reverted to the r20 optimum (57.2us, 1.9TB/s
// delivered = random-gather fabric rate). k_layer phase 1 is FROZEN.
// r23 (this round): structural traffic/launch cuts outside the gather --
// (a) pooling fused into L3 epilogue (lane-local dot + 16-lane reduce + one
//     atomicAdd/row; 100K adds ~ 16x below r5's convicted scale), deletes
//     k_pool + its 25.6MB read + L3's 25.6MB hout store;
// (b) k_init+k_wpack+out-init merged into k_prep (11 -> 9 launches);
// (c) k_range (boundary-store form, r22's verified win) moved before layers.

// ---- fp8 helpers (OCP e4m3 on gfx950) ----

__device__ __forceinline__ uint2 pack_fp8x8(const float* v) {
    int lo = 0, hi = 0;
    lo = __builtin_amdgcn_cvt_pk_fp8_f32(v[0], v[1], lo, false);
    lo = __builtin_amdgcn_cvt_pk_fp8_f32(v[2], v[3], lo, true);
    hi = __builtin_amdgcn_cvt_pk_fp8_f32(v[4], v[5], hi, false);
    hi = __builtin_amdgcn_cvt_pk_fp8_f32(v[6], v[7], hi, true);
    return (uint2){(unsigned)lo, (unsigned)hi};
}

__device__ __forceinline__ void acc_fp8x8(uint2 u, f32x2* a2) {
    a2[0] += __builtin_amdgcn_cvt_pk_f32_fp8((int)u.x, false);
    a2[1] += __builtin_amdgcn_cvt_pk_f32_fp8((int)u.x, true);
    a2[2] += __builtin_amdgcn_cvt_pk_f32_fp8((int)u.y, false);
    a2[3] += __builtin_amdgcn_cvt_pk_f32_fp8((int)u.y, true);
}

// ---------------- prep: bfill/gstart/gend/out init + W pack ----------------

__global__ __launch_bounds__(256) void k_prep(const float* __restrict__ W, _Float16* __restrict__ Wp,
                                              int* __restrict__ bfill, int* __restrict__ gstart,
                                              int* __restrict__ gend, float* __restrict__ out,
                                              const float* __restrict__ bout) {
    int i = blockIdx.x * 256 + threadIdx.x;   // 32 blocks = 8192 threads
    if (i <= NBKT) bfill[i] = 0;
    if (i < NG) { gstart[i] = NN; gend[i] = 0; out[i] = bout[0]; }
    {   // W pack: W[l][k][n] fp32 -> B-fragment-layout fp16 (8192 threads)
        int lane = i & 63;
        int idx = i >> 6;          // 0..127
        int nt = idx & 7;
        int ks = (idx >> 3) & 3;
        int l = idx >> 5;
        int q = lane >> 4, l15 = lane & 15;
        const float* Wl = W + (size_t)l * H * H;
        _Float16* o = Wp + (size_t)idx * 512 + lane * 8;
#pragma unroll
        for (int j = 0; j < 8; j++)
            o[j] = (_Float16)(Wl[(ks * 32 + q * 8 + j) * H + nt * 16 + l15]);
    }
}

// batch is sorted: graph ranges are contiguous. Boundary detection with plain
// stores; no atomics (r5 lesson: contended cross-XCD RMWs ping-pong via HBM).
__global__ void k_range(const int* __restrict__ batch, int* __restrict__ gstart, int* __restrict__ gend) {
    int n = blockIdx.x * 256 + threadIdx.x;
    if (n < NN) {
        int g = batch[n];
        if (n == 0) {
            gstart[g] = 0;
        } else {
            int gp = batch[n - 1];
            if (gp != g) { gstart[g] = n; gend[gp] = n; }
        }
        if (n == NN - 1) gend[g] = NN;
    }
}

// ---------------- bucketed CSR build ----------------

__global__ __launch_bounds__(256) void k_bscatter(const int* __restrict__ src, const int* __restrict__ dst,
                                                  int* __restrict__ bfill, unsigned int* __restrict__ ebuf) {
    __shared__ int lc[NBKT];
    __shared__ int lbase[NBKT];
    int t = threadIdx.x;
    for (int i = t; i < NBKT; i += 256) lc[i] = 0;
    __syncthreads();
    int base = blockIdx.x * EPB;
    int rank[8];
    int bk[8];
    unsigned pk[8];
#pragma unroll
    for (int i = 0; i < 8; i++) {
        int e = base + i * 256 + t;
        if (e < NE) {
            int d = dst[e];
            int s = src[e];
            int b = d >> 8;
            bk[i] = b;
            pk[i] = (unsigned)s | ((unsigned)(d & 255) << 17);
            rank[i] = atomicAdd(&lc[b], 1);
        } else bk[i] = -1;
    }
    __syncthreads();
    for (int i = t; i < NBKT; i += 256)
        lbase[i] = i * CAP + (lc[i] ? atomicAdd(&bfill[i], lc[i]) : 0);
    __syncthreads();
#pragma unroll
    for (int i = 0; i < 8; i++) {
        if (bk[i] >= 0)
            ebuf[lbase[bk[i]] + rank[i]] = pk[i];
    }
}

// One block per bucket (391 blocks): count -> dis, scan -> rps/rpe, scatter -> col.
__global__ __launch_bounds__(256) void k_bcsr(const unsigned int* __restrict__ ebuf,
                                              const int* __restrict__ bfill,
                                              int* __restrict__ rps, int* __restrict__ rpe,
                                              int* __restrict__ col, float* __restrict__ dis) {
    __shared__ int lcnt[256];
    __shared__ int lfill[256];
    __shared__ int tmp[256];
    int t = threadIdx.x;
    int b = blockIdx.x;
    int cb = b * CAP;
    int ecnt = bfill[b];
    int n0 = b << 8;
    int nb = min(256, NN - n0);

    lcnt[t] = 0;
    lfill[t] = 0;
    __syncthreads();

    for (int i = t; i < ecnt; i += 256) {
        unsigned p = ebuf[cb + i];
        atomicAdd(&lcnt[p >> 17], 1);
    }
    __syncthreads();

    if (t < nb) dis[n0 + t] = rsqrtf((float)(lcnt[t] + 1));

    int v = lcnt[t];
    tmp[t] = v;
    __syncthreads();
    for (int off = 1; off < 256; off <<= 1) {
        int x = (t >= off) ? tmp[t - off] : 0;
        __syncthreads();
        tmp[t] += x;
        __syncthreads();
    }
    lcnt[t] = tmp[t] - v;   // exclusive scan
    __syncthreads();

    if (t < nb) {
        rps[n0 + t] = cb + lcnt[t];
        rpe[n0 + t] = cb + ((t < 255) ? lcnt[t + 1] : ecnt);
    }

    for (int i = t; i < ecnt; i += 256) {
        unsigned p = ebuf[cb + i];
        int dl = p >> 17;
        int s = (int)(p & 0x1FFFFu);
        col[cb + lcnt[dl] + atomicAdd(&lfill[dl], 1)] = s;
    }
}

// ---------------- embed: hh = fp16(relu(x @ W_embed + b)); hp = fp8(hh * dis) ----------------

__global__ __launch_bounds__(256) void k_embed(const float* __restrict__ x, const float* __restrict__ W,
                                               const float* __restrict__ b, _Float16* __restrict__ hh,
                                               const float* __restrict__ dis, uint2* __restrict__ hp) {
    __shared__ float Ws[DIM0 * H];
    __shared__ float bs[H];
    __shared__ float xs[16 * DIM0];
    int tid = threadIdx.x;
    for (int i = tid; i < DIM0 * H; i += 256) Ws[i] = W[i];
    if (tid < H) bs[tid] = b[tid];
    if (tid < 16 * DIM0) xs[tid] = x[(size_t)blockIdx.x * (16 * DIM0) + tid];
    __syncthreads();
    int nl = tid >> 4;
    int node = blockIdx.x * 16 + nl;
    int l4 = tid & 15;
    float dn = dis[node];
    f16x8 o;
    float hv[8];
#pragma unroll
    for (int j = 0; j < 8; j++) {
        int c = l4 * 8 + j;
        float acc = bs[c];
#pragma unroll
        for (int k = 0; k < DIM0; k++) acc += xs[nl * DIM0 + k] * Ws[k * H + c];
        float r = fmaxf(acc, 0.f);
        o[j] = (_Float16)r;
        hv[j] = r * dn;
    }
    *(f16x8*)&hh[(size_t)node * H + l4 * 8] = o;
    hp[(size_t)node * 16 + l4] = pack_fp8x8(hv);
}

// ---------------- fused layer: hout = relu(LN(agg(hin) @ W + b)) + hin ----------------
// Phase 1 = FROZEN r20 optimum: 4 rounds x 4 nodes, quarter-per-node, depth-4
// rows, col-only prefetch, no barriers. Epilogue: mode 1 = store hout+hp;
// mode 0 (last layer) = fused global-mean-pool (dot Wout, reduce, atomicAdd).

__global__ __launch_bounds__(128, 8) void k_layer(const _Float16* __restrict__ hin,
                                                  _Float16* __restrict__ hout,
                                                  const uint2* __restrict__ hpin,
                                                  uint2* __restrict__ hpout,
                                                  const float* __restrict__ dis, const int* __restrict__ rps,
                                                  const int* __restrict__ rpe, const int* __restrict__ col,
                                                  const _Float16* __restrict__ Wp,
                                                  const float* __restrict__ bias,
                                                  const float* __restrict__ gamma,
                                                  const float* __restrict__ beta,
                                                  const int* __restrict__ batch,
                                                  const int* __restrict__ gstart,
                                                  const int* __restrict__ gend,
                                                  const float* __restrict__ Wout,
                                                  float* __restrict__ out,
                                                  int store_hp) {
    __shared__ _Float16 Ls[2][16][136];   // 8704 B
    int tid = threadIdx.x;
    int wave = tid >> 6;
    int lane = tid & 63;
    int q = lane >> 4, l4 = lane & 15;
    int nbase = blockIdx.x * 32 + wave * 16;   // 32 | NN, no tail

    // wave-wide prefetch of the 16 nodes' CSR ranges + dis
    int l16 = lane & 15;
    int ev0 = rps[nbase + l16];
    int ev1 = rpe[nbase + l16];
    float dv = dis[nbase + l16];

    // ---- phase 1: gather 16 nodes into Ls, 4 nodes per round ----
#pragma unroll 1
    for (int r = 0; r < 4; r++) {
        int nl = r * 4 + q;                 // node slot owned by this quarter
        int e0 = __shfl(ev0, nl, 64);
        int e1 = __shfl(ev1, nl, 64);
        float dn = __shfl(dv, nl, 64);
        int node = nbase + nl;

        f32x2 a2[4];
#pragma unroll
        for (int j = 0; j < 4; j++) a2[j] = (f32x2){0.f, 0.f};

        uint2 sv = hpin[(size_t)node * 16 + l4];   // self row, issued early

        int e = e0;
        int pc0 = 0, pc1 = 0, pc2 = 0, pc3 = 0;
        if (e < e1) {                       // prime col pipeline (clamped)
            int m = e1 - 1;
            pc0 = col[e];
            pc1 = col[(e + 1 < e1) ? e + 1 : m];
            pc2 = col[(e + 2 < e1) ? e + 2 : m];
            pc3 = col[(e + 3 < e1) ? e + 3 : m];
        }
#pragma unroll 1
        for (; e + 3 < e1; e += 4) {
            int s0 = pc0, s1 = pc1, s2 = pc2, s3 = pc3;
            int n0 = e + 4, n1 = e + 5, n2 = e + 6, n3 = e + 7;
            pc0 = col[(n0 < e1) ? n0 : e0];   // next-iter cols overlap row loads
            pc1 = col[(n1 < e1) ? n1 : e0];
            pc2 = col[(n2 < e1) ? n2 : e0];
            pc3 = col[(n3 < e1) ? n3 : e0];
            uint2 v0 = hpin[(size_t)s0 * 16 + l4];
            uint2 v1 = hpin[(size_t)s1 * 16 + l4];
            uint2 v2 = hpin[(size_t)s2 * 16 + l4];
            uint2 v3 = hpin[(size_t)s3 * 16 + l4];
            acc_fp8x8(v0, a2);
            acc_fp8x8(v1, a2);
            acc_fp8x8(v2, a2);
            acc_fp8x8(v3, a2);
        }
        // tail (<=3 edges): cols already prefetched
        int k = e1 - e;
        if (k > 0) { uint2 v = hpin[(size_t)pc0 * 16 + l4]; acc_fp8x8(v, a2); }
        if (k > 1) { uint2 v = hpin[(size_t)pc1 * 16 + l4]; acc_fp8x8(v, a2); }
        if (k > 2) { uint2 v = hpin[(size_t)pc2 * 16 + l4]; acc_fp8x8(v, a2); }

        acc_fp8x8(sv, a2);   // self-loop

        f16x8 o;
#pragma unroll
        for (int j = 0; j < 4; j++) {
            o[2 * j]     = (_Float16)(a2[j][0] * dn);
            o[2 * j + 1] = (_Float16)(a2[j][1] * dn);
        }
        *(f16x8*)&Ls[wave][nl][l4 * 8] = o;
    }

    // ---- phase 2: read A-fragments into registers, then GEMM + LN (Ls reused) ----
    f16x8 af[4];
#pragma unroll
    for (int ks = 0; ks < 4; ks++)
        af[ks] = *(const f16x8*)&Ls[wave][l4][ks * 32 + q * 8];

    float bb[8], gm[8], bt[8];
#pragma unroll
    for (int nt = 0; nt < 8; nt++) {
        bb[nt] = bias[nt * 16 + l4];
        gm[nt] = gamma[nt * 16 + l4];
        bt[nt] = beta[nt * 16 + l4];
    }

    const f16x8* wp8 = (const f16x8*)Wp;
    f32x4 acc[8];
#pragma unroll
    for (int nt = 0; nt < 8; nt++) {
        acc[nt] = (f32x4){0.f, 0.f, 0.f, 0.f};
#pragma unroll
        for (int ks = 0; ks < 4; ks++) {
            f16x8 bf = wp8[(ks * 8 + nt) * 64 + lane];
            acc[nt] = __builtin_amdgcn_mfma_f32_16x16x32_f16(af[ks], bf, acc[nt], 0, 0, 0);
        }
#pragma unroll
        for (int r = 0; r < 4; r++) acc[nt][r] += bb[nt];
    }

    float mu[4], rs[4];
#pragma unroll
    for (int r = 0; r < 4; r++) {
        float s = 0.f;
#pragma unroll
        for (int nt = 0; nt < 8; nt++) s += acc[nt][r];
#pragma unroll
        for (int off = 8; off > 0; off >>= 1) s += __shfl_xor(s, off, 64);
        mu[r] = s * (1.f / 128.f);
    }
#pragma unroll
    for (int r = 0; r < 4; r++) {
        float v = 0.f;
#pragma unroll
        for (int nt = 0; nt < 8; nt++) {
            float d = acc[nt][r] - mu[r];
            v += d * d;
        }
#pragma unroll
        for (int off = 8; off > 0; off >>= 1) v += __shfl_xor(v, off, 64);
        rs[r] = rsqrtf(v * (1.f / 128.f) + EPS);
    }

    // overwrite Ls with LN output (af already in registers)
#pragma unroll
    for (int nt = 0; nt < 8; nt++)
#pragma unroll
        for (int r = 0; r < 4; r++) {
            float o = fmaxf((acc[nt][r] - mu[r]) * rs[r] * gm[nt] + bt[nt], 0.f);
            Ls[wave][q * 4 + r][nt * 16 + l4] = (_Float16)o;
        }

    // epilogue: residual add (hin) + either store (hout + fp8 copy) or fused pool
    const f16x8* hi8 = (const f16x8*)hin;
    f16x8* ho8 = (f16x8*)hout;
    int ck = lane & 15;
    float wv[8];
    if (!store_hp) {
#pragma unroll
        for (int j = 0; j < 8; j++) wv[j] = Wout[ck * 8 + j];
    }
#pragma unroll
    for (int it = 0; it < 4; it++) {
        int c = it * 64 + lane;
        int rr = c >> 4;                // rr = it*4 + q; ck = lane & 15
        int row = nbase + rr;
        f16x8 ln = *(const f16x8*)&Ls[wave][rr][ck * 8];
        f16x8 res = hi8[(size_t)row * 16 + ck];
        if (store_hp) {
            float dn2 = __shfl(dv, rr, 64);
            f16x8 o;
            float hv[8];
#pragma unroll
            for (int j = 0; j < 8; j++) {
                float s = (float)ln[j] + (float)res[j];
                o[j] = (_Float16)s;
                hv[j] = s * dn2;
            }
            ho8[(size_t)row * 16 + ck] = o;
            hpout[(size_t)row * 16 + ck] = pack_fp8x8(hv);
        } else {
            // fused global-mean-pool: p = (ln+res) . Wout slice
            float p = 0.f;
#pragma unroll
            for (int j = 0; j < 8; j++)
                p += ((float)ln[j] + (float)res[j]) * wv[j];
            p += __shfl_xor(p, 1, 64);
            p += __shfl_xor(p, 2, 64);
            p += __shfl_xor(p, 4, 64);
            p += __shfl_xor(p, 8, 64);
            if (ck == 0) {
                int g = batch[row];
                float inv = 1.f / (float)max(gend[g] - gstart[g], 1);
                atomicAdd(&out[g], p * inv);
            }
        }
    }
}

// ---------------- launcher ----------------

extern "C" void kernel_launch(void* const* d_in, const int* in_sizes, int n_in,
                              void* d_out, int out_size, void* d_ws, size_t ws_size,
                              hipStream_t stream) {
    const float* x       = (const float*)d_in[0];
    const int*   edge    = (const int*)d_in[1];
    const int*   batch   = (const int*)d_in[2];
    const float* W_embed = (const float*)d_in[3];
    const float* b_embed = (const float*)d_in[4];
    const float* W_gnn   = (const float*)d_in[5];
    const float* b_gnn   = (const float*)d_in[6];
    const float* gamma   = (const float*)d_in[7];
    const float* beta    = (const float*)d_in[8];
    const float* W_out   = (const float*)d_in[9];
    const float* b_out   = (const float*)d_in[10];
    float* out = (float*)d_out;

    char* ws = (char*)d_ws;
    size_t off = 0;
    auto alloc = [&](size_t bytes) -> char* {
        char* p = ws + off;
        off += (bytes + 255) & ~(size_t)255;
        return p;
    };
    _Float16*     hh0  = (_Float16*)alloc((size_t)NN * H * 2);
    _Float16*     hh1  = (_Float16*)alloc((size_t)NN * H * 2);
    uint2*        hp0  = (uint2*)alloc((size_t)NN * H);       // fp8 gather copies
    uint2*        hp1  = (uint2*)alloc((size_t)NN * H);
    _Float16*     Wp   = (_Float16*)alloc((size_t)NL * 4 * 8 * 512 * 2);
    float*        dis  = (float*)alloc((size_t)NN * 4);
    int*          rps  = (int*)alloc((size_t)NN * 4);
    int*          rpe  = (int*)alloc((size_t)NN * 4);
    int*          col  = (int*)alloc((size_t)NBKT * CAP * 4);
    unsigned int* ebuf = (unsigned int*)alloc((size_t)NBKT * CAP * 4);
    int*          bfill = (int*)alloc((NBKT + 1) * 4);
    int*   gstart = (int*)alloc((size_t)NG * 4);
    int*   gend   = (int*)alloc((size_t)NG * 4);

    const int* srcp = edge;
    const int* dstp = edge + NE;

    k_prep<<<32, 256, 0, stream>>>(W_gnn, Wp, bfill, gstart, gend, out, b_out);
    k_range<<<(NN + 255) / 256, 256, 0, stream>>>(batch, gstart, gend);
    k_bscatter<<<NBB, 256, 0, stream>>>(srcp, dstp, bfill, ebuf);
    k_bcsr<<<NBKT, 256, 0, stream>>>(ebuf, bfill, rps, rpe, col, dis);
    k_embed<<<NN / 16, 256, 0, stream>>>(x, W_embed, b_embed, hh0, dis, hp0);

    // ping-pong: L0 hh0->hh1, L1 hh1->hh0, L2 hh0->hh1, L3 fused-pool -> out
    _Float16* hb[2] = {hh0, hh1};
    uint2*    hp[2] = {hp0, hp1};
    for (int l = 0; l < NL; l++) {
        k_layer<<<(NN + 31) / 32, 128, 0, stream>>>(hb[l & 1], hb[(l & 1) ^ 1],
                                                    hp[l & 1], hp[(l & 1) ^ 1],
                                                    dis, rps, rpe, col,
                                                    Wp + (size_t)l * 4 * 8 * 512,
                                                    b_gnn + l * H, gamma + l * H, beta + l * H,
                                                    batch, gstart, gend, W_out, out,
                                                    (l != NL - 1) ? 1 : 0);
    }
}

// Round 11
// 342.999 us; speedup vs baseline: 1.3029x; 1.0516x over previous
//
#include <hip/hip_runtime.h>

#define NN 100000
#define NE 1600000
#define DIM0 11
#define H 128
#define NL 4
#define NG 4096
#define EPS 1e-5f

#define NBKT 391       // buckets of 256 nodes: bucket = dst >> 8
#define CAP 5120       // fixed bucket capacity (mean 4096, sigma 64 -> 16 sigma)
#define EPB 2048       // edges per block in scatter phase
static constexpr int NBB = (NE + EPB - 1) / EPB;  // 782
#define PREP_B 32
#define RANGE_B 391    // (NN+255)/256
static constexpr int FRONT_B = PREP_B + RANGE_B + NBB + NN / 16;  // 32+391+782+6250

typedef _Float16 f16x8 __attribute__((ext_vector_type(8)));
typedef float f32x4 __attribute__((ext_vector_type(4)));
typedef float f32x2 __attribute__((ext_vector_type(2)));

// r23 post-mortem: L3 fused pool = slowest layer (63.5 vs 57.2) -- 100K
// device atomicAdd on 16KB out[] ping-pongs lines cross-XCD (WRITE 23.4MB vs
// 0.1MB real; r5 mechanism at smaller scale). r24 (this round):
// (a) L3 epilogue -> wave-level segmented reduction over the 16 sorted rows;
//     only segment-tail lanes atomicAdd (~1.7/wave, 10x cut).
// (b) front-end collapsed into ONE launch (k_front: Wpack+out-init | range |
//     bscatter | embed-hh): independent once bfill zero -> hipMemsetAsync and
//     gstart/gend init DELETED (only non-empty graphs are ever read; k_range
//     writes all of those). embed sheds dis dep: fp8 hp pack moved into
//     k_bcsr (bucket block owns exactly its 256 nodes' fresh dis).
// k_layer phase 1 = FROZEN r20 optimum (57.2us = random-gather fabric rate).

// ---- fp8 helpers (OCP e4m3 on gfx950) ----

__device__ __forceinline__ uint2 pack_fp8x8(const float* v) {
    int lo = 0, hi = 0;
    lo = __builtin_amdgcn_cvt_pk_fp8_f32(v[0], v[1], lo, false);
    lo = __builtin_amdgcn_cvt_pk_fp8_f32(v[2], v[3], lo, true);
    hi = __builtin_amdgcn_cvt_pk_fp8_f32(v[4], v[5], hi, false);
    hi = __builtin_amdgcn_cvt_pk_fp8_f32(v[6], v[7], hi, true);
    return (uint2){(unsigned)lo, (unsigned)hi};
}

__device__ __forceinline__ void acc_fp8x8(uint2 u, f32x2* a2) {
    a2[0] += __builtin_amdgcn_cvt_pk_f32_fp8((int)u.x, false);
    a2[1] += __builtin_amdgcn_cvt_pk_f32_fp8((int)u.x, true);
    a2[2] += __builtin_amdgcn_cvt_pk_f32_fp8((int)u.y, false);
    a2[3] += __builtin_amdgcn_cvt_pk_f32_fp8((int)u.y, true);
}

// ---------------- front: Wpack + out-init | range | bscatter | embed-hh ----------------

__global__ __launch_bounds__(256) void k_front(const float* __restrict__ W, _Float16* __restrict__ Wp,
                                               float* __restrict__ out, const float* __restrict__ bout,
                                               const int* __restrict__ batch, int* __restrict__ gstart,
                                               int* __restrict__ gend,
                                               const int* __restrict__ src, const int* __restrict__ dst,
                                               int* __restrict__ bfill, unsigned int* __restrict__ ebuf,
                                               const float* __restrict__ x, const float* __restrict__ We,
                                               const float* __restrict__ be, _Float16* __restrict__ hh) {
    __shared__ int lc[NBKT];
    __shared__ int lbase[NBKT];
    __shared__ float Ws[DIM0 * H];
    __shared__ float bs[H];
    __shared__ float xs[16 * DIM0];
    int bb = blockIdx.x;
    int t = threadIdx.x;

    if (bb < PREP_B) {
        // ---- prep: out init + W pack (8192 threads) ----
        int i = bb * 256 + t;
        if (i < NG) out[i] = bout[0];
        int lane = i & 63;
        int idx = i >> 6;          // 0..127
        int nt = idx & 7;
        int ks = (idx >> 3) & 3;
        int l = idx >> 5;
        int q = lane >> 4, l15 = lane & 15;
        const float* Wl = W + (size_t)l * H * H;
        _Float16* o = Wp + (size_t)idx * 512 + lane * 8;
#pragma unroll
        for (int j = 0; j < 8; j++)
            o[j] = (_Float16)(Wl[(ks * 32 + q * 8 + j) * H + nt * 16 + l15]);
    } else if (bb < PREP_B + RANGE_B) {
        // ---- range: batch sorted -> boundary stores, no atomics ----
        int n = (bb - PREP_B) * 256 + t;
        if (n < NN) {
            int g = batch[n];
            if (n == 0) {
                gstart[g] = 0;
            } else {
                int gp = batch[n - 1];
                if (gp != g) { gstart[g] = n; gend[gp] = n; }
            }
            if (n == NN - 1) gend[g] = NN;
        }
    } else if (bb < PREP_B + RANGE_B + NBB) {
        // ---- bscatter ----
        for (int i = t; i < NBKT; i += 256) lc[i] = 0;
        __syncthreads();
        int base = (bb - PREP_B - RANGE_B) * EPB;
        int rank[8];
        int bk[8];
        unsigned pk[8];
#pragma unroll
        for (int i = 0; i < 8; i++) {
            int e = base + i * 256 + t;
            if (e < NE) {
                int d = dst[e];
                int s = src[e];
                int b = d >> 8;
                bk[i] = b;
                pk[i] = (unsigned)s | ((unsigned)(d & 255) << 17);
                rank[i] = atomicAdd(&lc[b], 1);
            } else bk[i] = -1;
        }
        __syncthreads();
        for (int i = t; i < NBKT; i += 256)
            lbase[i] = i * CAP + (lc[i] ? atomicAdd(&bfill[i], lc[i]) : 0);
        __syncthreads();
#pragma unroll
        for (int i = 0; i < 8; i++) {
            if (bk[i] >= 0)
                ebuf[lbase[bk[i]] + rank[i]] = pk[i];
        }
    } else {
        // ---- embed: hh = fp16(relu(x @ We + be)) only (no dis dependency) ----
        int eb = bb - PREP_B - RANGE_B - NBB;
        for (int i = t; i < DIM0 * H; i += 256) Ws[i] = We[i];
        if (t < H) bs[t] = be[t];
        if (t < 16 * DIM0) xs[t] = x[(size_t)eb * (16 * DIM0) + t];
        __syncthreads();
        int nl = t >> 4;
        int node = eb * 16 + nl;
        int l4 = t & 15;
        f16x8 o;
#pragma unroll
        for (int j = 0; j < 8; j++) {
            int c = l4 * 8 + j;
            float acc = bs[c];
#pragma unroll
            for (int k = 0; k < DIM0; k++) acc += xs[nl * DIM0 + k] * Ws[k * H + c];
            o[j] = (_Float16)fmaxf(acc, 0.f);
        }
        *(f16x8*)&hh[(size_t)node * H + l4 * 8] = o;
    }
}

// ---------------- bucketed CSR build pass 2 + fp8 hp pack ----------------
// One block per bucket (391 blocks): count -> dis, scan -> rps/rpe, scatter
// -> col, then hp = fp8(hh * dis) for this bucket's 256 nodes.

__global__ __launch_bounds__(256) void k_bcsr(const unsigned int* __restrict__ ebuf,
                                              const int* __restrict__ bfill,
                                              int* __restrict__ rps, int* __restrict__ rpe,
                                              int* __restrict__ col, float* __restrict__ dis,
                                              const _Float16* __restrict__ hh, uint2* __restrict__ hp) {
    __shared__ int lcnt[256];
    __shared__ int lfill[256];
    __shared__ int tmp[256];
    __shared__ float dnsh[256];
    int t = threadIdx.x;
    int b = blockIdx.x;
    int cb = b * CAP;
    int ecnt = bfill[b];
    int n0 = b << 8;
    int nb = min(256, NN - n0);

    lcnt[t] = 0;
    lfill[t] = 0;
    __syncthreads();

    for (int i = t; i < ecnt; i += 256) {
        unsigned p = ebuf[cb + i];
        atomicAdd(&lcnt[p >> 17], 1);
    }
    __syncthreads();

    float dnv = rsqrtf((float)(lcnt[t] + 1));
    dnsh[t] = dnv;
    if (t < nb) dis[n0 + t] = dnv;

    int v = lcnt[t];
    tmp[t] = v;
    __syncthreads();
    for (int off = 1; off < 256; off <<= 1) {
        int x = (t >= off) ? tmp[t - off] : 0;
        __syncthreads();
        tmp[t] += x;
        __syncthreads();
    }
    lcnt[t] = tmp[t] - v;   // exclusive scan
    __syncthreads();

    if (t < nb) {
        rps[n0 + t] = cb + lcnt[t];
        rpe[n0 + t] = cb + ((t < 255) ? lcnt[t + 1] : ecnt);
    }

    for (int i = t; i < ecnt; i += 256) {
        unsigned p = ebuf[cb + i];
        int dl = p >> 17;
        int s = (int)(p & 0x1FFFFu);
        col[cb + lcnt[dl] + atomicAdd(&lfill[dl], 1)] = s;
    }

    __syncthreads();
    // fp8 pre-scaled gather copy for this bucket's nodes
    const f16x8* hh8 = (const f16x8*)hh;
    for (int idx = t; idx < nb * 16; idx += 256) {
        int nl = idx >> 4, l4 = idx & 15;
        f16x8 h8 = hh8[(size_t)(n0 + nl) * 16 + l4];
        float dn = dnsh[nl];
        float hv[8];
#pragma unroll
        for (int j = 0; j < 8; j++) hv[j] = (float)h8[j] * dn;
        hp[(size_t)(n0 + nl) * 16 + l4] = pack_fp8x8(hv);
    }
}

// ---------------- fused layer: hout = relu(LN(agg(hin) @ W + b)) + hin ----------------
// Phase 1 = FROZEN r20 optimum. Epilogue mode 1: store hout + fp8 copy.
// Mode 0 (last layer): fused mean-pool via segmented wave reduction --
// segment-tail lanes only do atomicAdd (sorted batch -> ascending g).

__global__ __launch_bounds__(128, 8) void k_layer(const _Float16* __restrict__ hin,
                                                  _Float16* __restrict__ hout,
                                                  const uint2* __restrict__ hpin,
                                                  uint2* __restrict__ hpout,
                                                  const float* __restrict__ dis, const int* __restrict__ rps,
                                                  const int* __restrict__ rpe, const int* __restrict__ col,
                                                  const _Float16* __restrict__ Wp,
                                                  const float* __restrict__ bias,
                                                  const float* __restrict__ gamma,
                                                  const float* __restrict__ beta,
                                                  const int* __restrict__ batch,
                                                  const int* __restrict__ gstart,
                                                  const int* __restrict__ gend,
                                                  const float* __restrict__ Wout,
                                                  float* __restrict__ out,
                                                  int store_hp) {
    __shared__ _Float16 Ls[2][16][136];   // 8704 B
    int tid = threadIdx.x;
    int wave = tid >> 6;
    int lane = tid & 63;
    int q = lane >> 4, l4 = lane & 15;
    int nbase = blockIdx.x * 32 + wave * 16;   // 32 | NN, no tail

    // wave-wide prefetch of the 16 nodes' CSR ranges + dis
    int l16 = lane & 15;
    int ev0 = rps[nbase + l16];
    int ev1 = rpe[nbase + l16];
    float dv = dis[nbase + l16];

    // ---- phase 1: gather 16 nodes into Ls, 4 nodes per round ----
#pragma unroll 1
    for (int r = 0; r < 4; r++) {
        int nl = r * 4 + q;                 // node slot owned by this quarter
        int e0 = __shfl(ev0, nl, 64);
        int e1 = __shfl(ev1, nl, 64);
        float dn = __shfl(dv, nl, 64);
        int node = nbase + nl;

        f32x2 a2[4];
#pragma unroll
        for (int j = 0; j < 4; j++) a2[j] = (f32x2){0.f, 0.f};

        uint2 sv = hpin[(size_t)node * 16 + l4];   // self row, issued early

        int e = e0;
        int pc0 = 0, pc1 = 0, pc2 = 0, pc3 = 0;
        if (e < e1) {                       // prime col pipeline (clamped)
            int m = e1 - 1;
            pc0 = col[e];
            pc1 = col[(e + 1 < e1) ? e + 1 : m];
            pc2 = col[(e + 2 < e1) ? e + 2 : m];
            pc3 = col[(e + 3 < e1) ? e + 3 : m];
        }
#pragma unroll 1
        for (; e + 3 < e1; e += 4) {
            int s0 = pc0, s1 = pc1, s2 = pc2, s3 = pc3;
            int n0 = e + 4, n1 = e + 5, n2 = e + 6, n3 = e + 7;
            pc0 = col[(n0 < e1) ? n0 : e0];   // next-iter cols overlap row loads
            pc1 = col[(n1 < e1) ? n1 : e0];
            pc2 = col[(n2 < e1) ? n2 : e0];
            pc3 = col[(n3 < e1) ? n3 : e0];
            uint2 v0 = hpin[(size_t)s0 * 16 + l4];
            uint2 v1 = hpin[(size_t)s1 * 16 + l4];
            uint2 v2 = hpin[(size_t)s2 * 16 + l4];
            uint2 v3 = hpin[(size_t)s3 * 16 + l4];
            acc_fp8x8(v0, a2);
            acc_fp8x8(v1, a2);
            acc_fp8x8(v2, a2);
            acc_fp8x8(v3, a2);
        }
        // tail (<=3 edges): cols already prefetched
        int k = e1 - e;
        if (k > 0) { uint2 v = hpin[(size_t)pc0 * 16 + l4]; acc_fp8x8(v, a2); }
        if (k > 1) { uint2 v = hpin[(size_t)pc1 * 16 + l4]; acc_fp8x8(v, a2); }
        if (k > 2) { uint2 v = hpin[(size_t)pc2 * 16 + l4]; acc_fp8x8(v, a2); }

        acc_fp8x8(sv, a2);   // self-loop

        f16x8 o;
#pragma unroll
        for (int j = 0; j < 4; j++) {
            o[2 * j]     = (_Float16)(a2[j][0] * dn);
            o[2 * j + 1] = (_Float16)(a2[j][1] * dn);
        }
        *(f16x8*)&Ls[wave][nl][l4 * 8] = o;
    }

    // ---- phase 2: read A-fragments into registers, then GEMM + LN (Ls reused) ----
    f16x8 af[4];
#pragma unroll
    for (int ks = 0; ks < 4; ks++)
        af[ks] = *(const f16x8*)&Ls[wave][l4][ks * 32 + q * 8];

    float bb[8], gm[8], bt[8];
#pragma unroll
    for (int nt = 0; nt < 8; nt++) {
        bb[nt] = bias[nt * 16 + l4];
        gm[nt] = gamma[nt * 16 + l4];
        bt[nt] = beta[nt * 16 + l4];
    }

    const f16x8* wp8 = (const f16x8*)Wp;
    f32x4 acc[8];
#pragma unroll
    for (int nt = 0; nt < 8; nt++) {
        acc[nt] = (f32x4){0.f, 0.f, 0.f, 0.f};
#pragma unroll
        for (int ks = 0; ks < 4; ks++) {
            f16x8 bf = wp8[(ks * 8 + nt) * 64 + lane];
            acc[nt] = __builtin_amdgcn_mfma_f32_16x16x32_f16(af[ks], bf, acc[nt], 0, 0, 0);
        }
#pragma unroll
        for (int r = 0; r < 4; r++) acc[nt][r] += bb[nt];
    }

    float mu[4], rs[4];
#pragma unroll
    for (int r = 0; r < 4; r++) {
        float s = 0.f;
#pragma unroll
        for (int nt = 0; nt < 8; nt++) s += acc[nt][r];
#pragma unroll
        for (int off = 8; off > 0; off >>= 1) s += __shfl_xor(s, off, 64);
        mu[r] = s * (1.f / 128.f);
    }
#pragma unroll
    for (int r = 0; r < 4; r++) {
        float v = 0.f;
#pragma unroll
        for (int nt = 0; nt < 8; nt++) {
            float d = acc[nt][r] - mu[r];
            v += d * d;
        }
#pragma unroll
        for (int off = 8; off > 0; off >>= 1) v += __shfl_xor(v, off, 64);
        rs[r] = rsqrtf(v * (1.f / 128.f) + EPS);
    }

    // overwrite Ls with LN output (af already in registers)
#pragma unroll
    for (int nt = 0; nt < 8; nt++)
#pragma unroll
        for (int r = 0; r < 4; r++) {
            float o = fmaxf((acc[nt][r] - mu[r]) * rs[r] * gm[nt] + bt[nt], 0.f);
            Ls[wave][q * 4 + r][nt * 16 + l4] = (_Float16)o;
        }

    // epilogue
    const f16x8* hi8 = (const f16x8*)hin;
    f16x8* ho8 = (f16x8*)hout;
    int ck = lane & 15;
    if (store_hp) {
#pragma unroll
        for (int it = 0; it < 4; it++) {
            int c = it * 64 + lane;
            int rr = c >> 4;
            int row = nbase + rr;
            f16x8 ln = *(const f16x8*)&Ls[wave][rr][ck * 8];
            f16x8 res = hi8[(size_t)row * 16 + ck];
            float dn2 = __shfl(dv, rr, 64);
            f16x8 o;
            float hv[8];
#pragma unroll
            for (int j = 0; j < 8; j++) {
                float s = (float)ln[j] + (float)res[j];
                o[j] = (_Float16)s;
                hv[j] = s * dn2;
            }
            ho8[(size_t)row * 16 + ck] = o;
            hpout[(size_t)row * 16 + ck] = pack_fp8x8(hv);
        }
    } else {
        // fused global-mean-pool with segmented wave reduction
        float wv[8];
#pragma unroll
        for (int j = 0; j < 8; j++) wv[j] = Wout[ck * 8 + j];
        float pv[4];
#pragma unroll
        for (int it = 0; it < 4; it++) {
            int c = it * 64 + lane;
            int rr = c >> 4;
            int row = nbase + rr;
            f16x8 ln = *(const f16x8*)&Ls[wave][rr][ck * 8];
            f16x8 res = hi8[(size_t)row * 16 + ck];
            float p = 0.f;
#pragma unroll
            for (int j = 0; j < 8; j++)
                p += ((float)ln[j] + (float)res[j]) * wv[j];
            p += __shfl_xor(p, 1, 64);
            p += __shfl_xor(p, 2, 64);
            p += __shfl_xor(p, 4, 64);
            p += __shfl_xor(p, 8, 64);
            pv[it] = p;   // replicated across the 16-lane quarter
        }
        // redistribute: lane l16 takes row l16's value (src lane (l16&3)*16, slot l16>>2)
        int srcl = (l16 & 3) << 4;
        float s0 = __shfl(pv[0], srcl, 64);
        float s1 = __shfl(pv[1], srcl, 64);
        float s2 = __shfl(pv[2], srcl, 64);
        float s3 = __shfl(pv[3], srcl, 64);
        float v = (l16 < 4) ? s0 : (l16 < 8) ? s1 : (l16 < 12) ? s2 : s3;
        int g = batch[nbase + l16];
        // segmented inclusive sum (g ascending over rows; 16-lane groups)
#pragma unroll
        for (int off = 1; off < 16; off <<= 1) {
            float vn = __shfl(v, lane - off, 64);
            int gn = __shfl(g, lane - off, 64);
            if (l16 >= off && gn == g) v += vn;
        }
        int gnx = __shfl(g, lane + 1, 64);
        if (lane < 16 && ((l16 == 15) || (gnx != g))) {
            float inv = 1.f / (float)max(gend[g] - gstart[g], 1);
            atomicAdd(&out[g], v * inv);
        }
    }
}

// ---------------- launcher ----------------

extern "C" void kernel_launch(void* const* d_in, const int* in_sizes, int n_in,
                              void* d_out, int out_size, void* d_ws, size_t ws_size,
                              hipStream_t stream) {
    const float* x       = (const float*)d_in[0];
    const int*   edge    = (const int*)d_in[1];
    const int*   batch   = (const int*)d_in[2];
    const float* W_embed = (const float*)d_in[3];
    const float* b_embed = (const float*)d_in[4];
    const float* W_gnn   = (const float*)d_in[5];
    const float* b_gnn   = (const float*)d_in[6];
    const float* gamma   = (const float*)d_in[7];
    const float* beta    = (const float*)d_in[8];
    const float* W_out   = (const float*)d_in[9];
    const float* b_out   = (const float*)d_in[10];
    float* out = (float*)d_out;

    char* ws = (char*)d_ws;
    size_t off = 0;
    auto alloc = [&](size_t bytes) -> char* {
        char* p = ws + off;
        off += (bytes + 255) & ~(size_t)255;
        return p;
    };
    _Float16*     hh0  = (_Float16*)alloc((size_t)NN * H * 2);
    _Float16*     hh1  = (_Float16*)alloc((size_t)NN * H * 2);
    uint2*        hp0  = (uint2*)alloc((size_t)NN * H);       // fp8 gather copies
    uint2*        hp1  = (uint2*)alloc((size_t)NN * H);
    _Float16*     Wp   = (_Float16*)alloc((size_t)NL * 4 * 8 * 512 * 2);
    float*        dis  = (float*)alloc((size_t)NN * 4);
    int*          rps  = (int*)alloc((size_t)NN * 4);
    int*          rpe  = (int*)alloc((size_t)NN * 4);
    int*          col  = (int*)alloc((size_t)NBKT * CAP * 4);
    unsigned int* ebuf = (unsigned int*)alloc((size_t)NBKT * CAP * 4);
    int*          bfill = (int*)alloc((NBKT + 1) * 4);
    int*   gstart = (int*)alloc((size_t)NG * 4);
    int*   gend   = (int*)alloc((size_t)NG * 4);

    const int* srcp = edge;
    const int* dstp = edge + NE;

    hipMemsetAsync(bfill, 0, (NBKT + 1) * sizeof(int), stream);
    k_front<<<FRONT_B, 256, 0, stream>>>(W_gnn, Wp, out, b_out,
                                         batch, gstart, gend,
                                         srcp, dstp, bfill, ebuf,
                                         x, W_embed, b_embed, hh0);
    k_bcsr<<<NBKT, 256, 0, stream>>>(ebuf, bfill, rps, rpe, col, dis, hh0, hp0);

    // ping-pong: L0 hh0->hh1, L1 hh1->hh0, L2 hh0->hh1, L3 fused-pool -> out
    _Float16* hb[2] = {hh0, hh1};
    uint2*    hp[2] = {hp0, hp1};
    for (int l = 0; l < NL; l++) {
        k_layer<<<(NN + 31) / 32, 128, 0, stream>>>(hb[l & 1], hb[(l & 1) ^ 1],
                                                    hp[l & 1], hp[(l & 1) ^ 1],
                                                    dis, rps, rpe, col,
                                                    Wp + (size_t)l * 4 * 8 * 512,
                                                    b_gnn + l * H, gamma + l * H, beta + l * H,
                                                    batch, gstart, gend, W_out, out,
                                                    (l != NL - 1) ? 1 : 0);
    }
}